// Round 11
// baseline (2680.671 us; speedup 1.0000x reference)
//
#include <hip/hip_runtime.h>
#include <stdint.h>
#include <stddef.h>

typedef __attribute__((ext_vector_type(8))) _Float16 half8;
typedef __attribute__((ext_vector_type(8))) unsigned short ushort8;
typedef __attribute__((ext_vector_type(4))) float f4;

namespace {
constexpr int kSteps = 255;   // reference iterates t = 0 .. T-2
constexpr int KTOT = 1152;    // 1024 (h) + 128 (x)

// workspace layout (bytes); total ~45 MB
// h layout: [group(4)][ub(64)][row(128)][u(16)] fp16 -> block-contiguous 4KB slices
constexpr size_t OFF_H0   = 0;                                   // 1 MB  h ping
constexpr size_t OFF_CNT  = (size_t)1 << 20;                     // 4 KB  counters + inv flags
constexpr size_t OFF_H1   = ((size_t)1 << 20) + 4096;            // 1 MB  h pong
constexpr size_t OFF_BSUM = OFF_H1 + ((size_t)1 << 20);          // 16 KB b_ih+b_hh (fp32)
constexpr size_t OFF_WCAT = OFF_BSUM + 16384;                    // 9.4 MB fp16 [4096][1152]
constexpr size_t OFF_XT   = OFF_WCAT + (size_t)4096 * KTOT * 2;  // 33.4 MB fp16 [255][512][128]
}

__device__ __forceinline__ unsigned short f2h(float f) {
  _Float16 h = (_Float16)f;
  return __builtin_bit_cast(unsigned short, h);
}
__device__ __forceinline__ float h2f(unsigned short s) {
  return (float)__builtin_bit_cast(_Float16, s);
}

// ---------- prep 1: Wcat fp16 + bsum ----------
__global__ void prep_wcat(const float* __restrict__ Wih, const float* __restrict__ Whh,
                          const float* __restrict__ bih, const float* __restrict__ bhh,
                          char* __restrict__ ws) {
  if (blockIdx.x < 2304) {
    unsigned gid = blockIdx.x * 256 + threadIdx.x;
    unsigned row = gid / 144, cc = gid % 144;
    const float* src = (cc < 128) ? (Whh + (size_t)row * 1024 + (size_t)cc * 8)
                                  : (Wih + (size_t)row * 128 + (size_t)(cc - 128) * 8);
    ushort8 o;
#pragma unroll
    for (int j = 0; j < 8; j++) o[j] = f2h(src[j]);
    *(ushort8*)((unsigned short*)(ws + OFF_WCAT) + (size_t)row * KTOT + cc * 8) = o;
  } else {
    int i = (blockIdx.x - 2304) * 256 + threadIdx.x;
    ((float*)(ws + OFF_BSUM))[i] = bih[i] + bhh[i];
  }
}

// ---------- prep 2: xT[t][b][i] = fp16(x[b][i][t]) ----------
__global__ void prep_xt(const float* __restrict__ x, char* __restrict__ ws) {
  unsigned short* xT = (unsigned short*)(ws + OFF_XT);
  __shared__ unsigned short tile[128][72];
  const int b = blockIdx.x >> 2;
  const int t0 = (blockIdx.x & 3) * 64;
  const int wv = threadIdx.x >> 6, tl = threadIdx.x & 63;
  if (t0 + tl < 255) {
#pragma unroll
    for (int ii = 0; ii < 32; ii++) {
      int i = wv + ii * 4;
      tile[i][tl] = f2h(x[((size_t)b * 128 + i) * 256 + t0 + tl]);
    }
  }
  __syncthreads();
  const int tl2 = threadIdx.x >> 4, ic = threadIdx.x & 15;
#pragma unroll
  for (int pp = 0; pp < 4; pp++) {
    int tloc = pp * 16 + tl2;
    int t = t0 + tloc;
    if (t < 255) {
      ushort8 v;
#pragma unroll
      for (int j = 0; j < 8; j++) v[j] = tile[ic * 8 + j][tloc];
      *(ushort8*)&xT[((size_t)t * 512 + b) * 128 + ic * 8] = v;
    }
  }
}

// counted-vmcnt + barrier (T3/T4)
#define WAITBAR(N) do { \
    asm volatile("s_waitcnt vmcnt(" #N ") lgkmcnt(0)\n\ts_barrier" ::: "memory"); \
    __builtin_amdgcn_sched_barrier(0); \
  } while (0)

// ---------- persistent LSTM kernel (r10 skeleton) ----------
// grid 256 = 4 groups (128 rows) x 64 unit-blocks (16 units). 8 waves = 4K x 2N.
// Coherence v3: h stores write-through (sc0 sc1) -> LLC always fresh; nothing dirty
// anywhere. h LOADS are L2-cached; staleness handled by ONE buffer_inv per
// (XCD, group) per step (CAS-elected leader after the group rendezvous) ->
// ~8 blocks/XCD share each h line through L2 instead of slamming LLC (64->8 MB/step).
__global__ __launch_bounds__(512, 1) void lstm_persist(char* __restrict__ ws) {
  const unsigned short* __restrict__ wcat = (const unsigned short*)(ws + OFF_WCAT);
  const float* __restrict__ bsum = (const float*)(ws + OFF_BSUM);
  const unsigned short* __restrict__ xT = (const unsigned short*)(ws + OFF_XT);
  unsigned short* h0 = (unsigned short*)(ws + OFF_H0);
  unsigned short* h1 = (unsigned short*)(ws + OFF_H1);

  __shared__ __align__(16) unsigned short Ab[4][16384];   // 4 x 32KB chunk bufs / reduce scratch

  const int tid = threadIdx.x;
  const int lane = tid & 63;
  const int w = tid >> 6;
  const int wk = w & 3;           // K group (k-slice parity mod 4)
  const int wn = w >> 2;          // N half
  const int l15 = lane & 15, l4 = lane >> 4;
  const int gblk = blockIdx.x >> 6;
  const int cblk = blockIdx.x & 63;
  const int B0 = gblk * 128;
  const int U0 = cblk * 16;
  int* cntp = (int*)(ws + OFF_CNT) + gblk * 16;

  // per-(XCD, group) inv-leader flag cell (64B apart; zeroed by host memset)
  unsigned xcc;
  asm volatile("s_getreg_b32 %0, hwreg(HW_REG_XCC_ID)" : "=s"(xcc));
  int* flagp = (int*)(ws + OFF_CNT + 1024 + ((size_t)(xcc & 7) * 4 + gblk) * 64);

  // ---- weight fragments -> registers (col n = wn*32+nf*16+l15 -> unit n>>2, gate n&3) ----
  half8 bf[9][2];
  float bs[2];
#pragma unroll
  for (int nf = 0; nf < 2; nf++) {
    int u = wn * 8 + nf * 4 + (l15 >> 2);
    int R = (l15 & 3) * 1024 + U0 + u;          // PyTorch gate order i,f,g,o
    bs[nf] = bsum[R];
#pragma unroll
    for (int c = 0; c < 9; c++)
      bf[c][nf] = *(const half8*)&wcat[(size_t)R * KTOT + c * 128 + wk * 32 + l4 * 8];
  }
  const float bseed0 = (wk == 0) ? bs[0] : 0.f;
  const float bseed1 = (wk == 0) ? bs[1] : 0.f;

  // ---- staging: 32 slots of 1KB per 32KB chunk; slot s = w*4+i (wave-uniform LDS base) ----
  // LDS (row, c16) holds G(row, c16 ^ (row&7)); source pre-inverse-swizzled (rule #21).
  int hoffc[4], xoff[4];
#pragma unroll
  for (int i = 0; i < 4; i++) {
    int s = w * 4 + i;
    int row = s * 4 + (lane >> 4);
    int cg = (lane & 15) ^ (row & 7);
    hoffc[i] = (cg >> 1) * 2048 + row * 16 + (cg & 1) * 8;   // + c*16384 per chunk
    xoff[i] = (B0 + row) * 128 + cg * 8;
  }
  // A ds_read: row = m*16+l15, c16 = (wk*4+l4) ^ (l15&7)
  const int aBase = l15 * 256 + (((wk * 4 + l4) ^ (l15 & 7)) * 16);

  // reduce-exchange swizzle constants (writer side)
  int nb16[2], hn[2];
#pragma unroll
  for (int nf = 0; nf < 2; nf++) {
    int n = wn * 32 + nf * 16 + l15;
    nb16[nf] = n * 32;
    hn[nf] = (n ^ (n >> 3)) & 7;
  }
  // reader side: thread owns cells (rows 4*rfr..4*rfr+3, unit ucell)
  const int ucell = tid & 15;
  const int rfr = tid >> 4;
  int ra16[4];
#pragma unroll
  for (int g2 = 0; g2 < 4; g2++) {
    int n = 4 * ucell + g2;
    ra16[g2] = n * 32 + (rfr ^ ((n ^ (n >> 3)) & 7));
  }
  char* lds = (char*)&Ab[0][0];

  f4 acc[8][2];

// h loads: NORMAL caching -> L2-shared across the ~8 co-XCD blocks of this group
#define STAGE_H(C, BUF) do { \
    _Pragma("unroll") \
    for (int i = 0; i < 4; i++) \
      __builtin_amdgcn_global_load_lds( \
          (const __attribute__((address_space(1))) void*)(hsrcg + hoffc[i] + (C) * 16384), \
          (__attribute__((address_space(3))) void*)((char*)&Ab[BUF][0] + (w * 4 + i) * 1024), \
          16, 0, 0); \
  } while (0)

#define STAGE_X() do { \
    _Pragma("unroll") \
    for (int i = 0; i < 4; i++) \
      __builtin_amdgcn_global_load_lds( \
          (const __attribute__((address_space(1))) void*)(xslab + xoff[i]), \
          (__attribute__((address_space(3))) void*)((char*)&Ab[3][0] + (w * 4 + i) * 1024), \
          16, 0, 0); \
  } while (0)

#define COMPUTE(C, BUF) do { \
    const char* _b = (const char*)&Ab[BUF][0] + aBase; \
    half8 a0 = *(const half8*)(_b); \
    half8 a1 = *(const half8*)(_b + 4096); \
    half8 a2 = *(const half8*)(_b + 8192); \
    half8 a3 = *(const half8*)(_b + 12288); \
    half8 a4 = *(const half8*)(_b + 16384); \
    half8 a5 = *(const half8*)(_b + 20480); \
    half8 a6 = *(const half8*)(_b + 24576); \
    half8 a7 = *(const half8*)(_b + 28672); \
    acc[0][0] = __builtin_amdgcn_mfma_f32_16x16x32_f16(a0, bf[C][0], acc[0][0], 0, 0, 0); \
    acc[0][1] = __builtin_amdgcn_mfma_f32_16x16x32_f16(a0, bf[C][1], acc[0][1], 0, 0, 0); \
    acc[1][0] = __builtin_amdgcn_mfma_f32_16x16x32_f16(a1, bf[C][0], acc[1][0], 0, 0, 0); \
    acc[1][1] = __builtin_amdgcn_mfma_f32_16x16x32_f16(a1, bf[C][1], acc[1][1], 0, 0, 0); \
    acc[2][0] = __builtin_amdgcn_mfma_f32_16x16x32_f16(a2, bf[C][0], acc[2][0], 0, 0, 0); \
    acc[2][1] = __builtin_amdgcn_mfma_f32_16x16x32_f16(a2, bf[C][1], acc[2][1], 0, 0, 0); \
    acc[3][0] = __builtin_amdgcn_mfma_f32_16x16x32_f16(a3, bf[C][0], acc[3][0], 0, 0, 0); \
    acc[3][1] = __builtin_amdgcn_mfma_f32_16x16x32_f16(a3, bf[C][1], acc[3][1], 0, 0, 0); \
    acc[4][0] = __builtin_amdgcn_mfma_f32_16x16x32_f16(a4, bf[C][0], acc[4][0], 0, 0, 0); \
    acc[4][1] = __builtin_amdgcn_mfma_f32_16x16x32_f16(a4, bf[C][1], acc[4][1], 0, 0, 0); \
    acc[5][0] = __builtin_amdgcn_mfma_f32_16x16x32_f16(a5, bf[C][0], acc[5][0], 0, 0, 0); \
    acc[5][1] = __builtin_amdgcn_mfma_f32_16x16x32_f16(a5, bf[C][1], acc[5][1], 0, 0, 0); \
    acc[6][0] = __builtin_amdgcn_mfma_f32_16x16x32_f16(a6, bf[C][0], acc[6][0], 0, 0, 0); \
    acc[6][1] = __builtin_amdgcn_mfma_f32_16x16x32_f16(a6, bf[C][1], acc[6][1], 0, 0, 0); \
    acc[7][0] = __builtin_amdgcn_mfma_f32_16x16x32_f16(a7, bf[C][0], acc[7][0], 0, 0, 0); \
    acc[7][1] = __builtin_amdgcn_mfma_f32_16x16x32_f16(a7, bf[C][1], acc[7][1], 0, 0, 0); \
  } while (0)

  f4 creg = {0.f, 0.f, 0.f, 0.f};   // 4 cells (rows 4*rfr+j, unit ucell)

#pragma unroll 1
  for (int t = 0; t < kSteps; t++) {
    const unsigned short* hsrcg = ((t & 1) ? h1 : h0) + gblk * 131072;
    unsigned short* hdst = (t & 1) ? h0 : h1;
    const unsigned short* xslab = xT + (size_t)t * (512 * 128);

#pragma unroll
    for (int m = 0; m < 8; m++) {
      acc[m][0] = (f4){bseed0, bseed0, bseed0, bseed0};
      acc[m][1] = (f4){bseed1, bseed1, bseed1, bseed1};
    }

    STAGE_X();                   // flies during the group-barrier wait

    if (tid == 0) {
      // 1) group rendezvous: all 64 blocks of this group finished step t-1
      int target = 64 * t;
      int guard = 1 << 18;
      while (guard--) {
        int c;
        asm volatile("global_load_dword %0, %1, off sc0 sc1\n\ts_waitcnt vmcnt(0)"
                     : "=v"(c) : "v"(cntp) : "memory");
        if (c >= target) break;
        __builtin_amdgcn_s_sleep(2);
      }
      // 2) per-(XCD,group) inv leader: exactly one L2 invalidate per step.
      //    Safe: nothing is ever dirty (h write-through; prep output flushed at
      //    kernel boundary). Inv is after writers done (spin passed) and before
      //    any (xcd,group) reader load (they wait for flag).
      int expected = t;
      bool leader = __hip_atomic_compare_exchange_strong(
          flagp, &expected, -(t + 1), __ATOMIC_RELAXED, __ATOMIC_RELAXED,
          __HIP_MEMORY_SCOPE_AGENT);
      if (leader) {
        asm volatile("buffer_inv sc0 sc1\n\ts_waitcnt vmcnt(0)" ::: "memory");
        int done = t + 1;
        asm volatile("global_store_dword %0, %1, off sc0 sc1"
                     :: "v"(flagp), "v"(done) : "memory");
      } else {
        int g2 = 1 << 18;
        while (g2--) {
          int v;
          asm volatile("global_load_dword %0, %1, off sc0 sc1\n\ts_waitcnt vmcnt(0)"
                       : "=v"(v) : "v"(flagp) : "memory");
          if (v == t + 1) break;
          __builtin_amdgcn_s_sleep(1);
        }
        // own-CU L1 may hold this block's step t-2 h lines: cheap local inv
        asm volatile("buffer_inv sc0\n\ts_waitcnt vmcnt(0)" ::: "memory");
      }
    }
    __syncthreads();             // join; drains x staging (vmcnt 0)

    // r8-proven 2-deep schedule (8 loads in flight; overwrite >= 1 barrier after last read)
    STAGE_H(0, 0); STAGE_H(1, 1);
    COMPUTE(8, 3);                    // x contribution (buf3 resident)
    STAGE_H(2, 2);
    WAITBAR(8);  COMPUTE(0, 0);
    STAGE_H(3, 3);
    WAITBAR(8);  COMPUTE(1, 1);
    STAGE_H(4, 0);
    WAITBAR(8);  COMPUTE(2, 2);
    STAGE_H(5, 1);
    WAITBAR(8);  COMPUTE(3, 3);
    STAGE_H(6, 2);
    WAITBAR(8);  COMPUTE(4, 0);
    STAGE_H(7, 3);
    WAITBAR(8);  COMPUTE(5, 1);
    WAITBAR(4);  COMPUTE(6, 2);
    WAITBAR(0);  COMPUTE(7, 3);

    // ---- 4-way K reduction through LDS (128KB over bufs 0-3) ----
    asm volatile("s_waitcnt lgkmcnt(0)\n\ts_barrier" ::: "memory");  // staging reads done
#pragma unroll
    for (int m = 0; m < 8; m++)
#pragma unroll
      for (int nf = 0; nf < 2; nf++) {
        int rf = m * 4 + l4;
        *(f4*)(lds + (size_t)(wk * 2048 + nb16[nf] + (rf ^ hn[nf])) * 16) = acc[m][nf];
      }
    __syncthreads();
    {
      f4 gs[4];
#pragma unroll
      for (int g2 = 0; g2 < 4; g2++) {
        f4 v0 = *(const f4*)(lds + (size_t)ra16[g2] * 16);
        f4 v1 = *(const f4*)(lds + 32768 + (size_t)ra16[g2] * 16);
        f4 v2 = *(const f4*)(lds + 65536 + (size_t)ra16[g2] * 16);
        f4 v3 = *(const f4*)(lds + 98304 + (size_t)ra16[g2] * 16);
        gs[g2] = (v0 + v1) + (v2 + v3);
      }
      size_t hb = (size_t)((gblk * 64 + cblk) * 128 + rfr * 4) * 16 + ucell;
#pragma unroll
      for (int j = 0; j < 4; j++) {
        float ig = 1.f / (1.f + __expf(-gs[0][j]));
        float fg = 1.f / (1.f + __expf(-gs[1][j]));
        float gg = 2.f / (1.f + __expf(-2.f * gs[2][j])) - 1.f;
        float og = 1.f / (1.f + __expf(-gs[3][j]));
        float cn = fg * creg[j] + ig * gg;
        creg[j] = cn;
        float th = 2.f / (1.f + __expf(-2.f * cn)) - 1.f;
        // write-through to LLC: coherent across XCDs, leaves no dirty L2 line
        unsigned short* hp = hdst + hb + (size_t)j * 16;
        unsigned hv = f2h(og * th);
        asm volatile("global_store_short %0, %1, off sc0 sc1"
                     :: "v"(hp), "v"(hv) : "memory");
      }
    }
    __syncthreads();             // drains h stores (ack'd at LLC) + reduce reads
    if (tid == 0)                // RELAXED: no buffer_wbl2 (nothing dirty to flush)
      __hip_atomic_fetch_add(cntp, 1, __ATOMIC_RELAXED, __HIP_MEMORY_SCOPE_AGENT);
  }
#undef STAGE_H
#undef STAGE_X
#undef COMPUTE
}

// ---------- FC: out = h_last @ W_fc^T + b_fc ----------
__global__ void fc_kernel(const char* __restrict__ ws, const float* __restrict__ Wfc,
                          const float* __restrict__ bfc, float* __restrict__ out) {
  const unsigned short* h = (const unsigned short*)(ws + OFF_H1);  // t=254 writes h1
  int o = threadIdx.x & 127;
  int b = blockIdx.x * 2 + (threadIdx.x >> 7);
  const float* wrow = Wfc + (size_t)o * 1024;
  float acc = bfc[o];
  int gb = b >> 7, rb = b & 127;
#pragma unroll 4
  for (int k = 0; k < 1024; k += 8) {
    ushort8 hv = *(const ushort8*)&h[((size_t)(gb * 64 + (k >> 4)) * 128 + rb) * 16 + (k & 15)];
    f4 w0 = *(const f4*)&wrow[k];
    f4 w1 = *(const f4*)&wrow[k + 4];
#pragma unroll
    for (int j = 0; j < 4; j++) acc += h2f(hv[j]) * w0[j];
#pragma unroll
    for (int j = 0; j < 4; j++) acc += h2f(hv[4 + j]) * w1[j];
  }
  out[(size_t)b * 128 + o] = acc;
}

extern "C" void kernel_launch(void* const* d_in, const int* in_sizes, int n_in,
                              void* d_out, int out_size, void* d_ws, size_t ws_size,
                              hipStream_t stream) {
  const float* x   = (const float*)d_in[0];
  const float* Wih = (const float*)d_in[1];
  const float* Whh = (const float*)d_in[2];
  const float* bih = (const float*)d_in[3];
  const float* bhh = (const float*)d_in[4];
  const float* Wfc = (const float*)d_in[5];
  const float* bfc = (const float*)d_in[6];
  char* ws = (char*)d_ws;

  hipMemsetAsync(ws + OFF_H0, 0, ((size_t)1 << 20) + 4096, stream);
  prep_wcat<<<2320, 256, 0, stream>>>(Wih, Whh, bih, bhh, ws);
  prep_xt<<<2048, 256, 0, stream>>>(x, ws);
  lstm_persist<<<256, 512, 0, stream>>>(ws);
  fc_kernel<<<256, 256, 0, stream>>>(ws, Wfc, bfc, (float*)d_out);
}

// Round 12
// 2376.919 us; speedup vs baseline: 1.1278x; 1.1278x over previous
//
#include <hip/hip_runtime.h>
#include <stdint.h>
#include <stddef.h>

typedef __attribute__((ext_vector_type(8))) _Float16 half8;
typedef __attribute__((ext_vector_type(8))) unsigned short ushort8;
typedef __attribute__((ext_vector_type(4))) float f4;

namespace {
constexpr int kSteps = 255;   // reference iterates t = 0 .. T-2
constexpr int KTOT = 1152;    // 1024 (h) + 128 (x)

// workspace layout (bytes); total ~45 MB
// h layout: [group(4)][ub(64)][row(128)][u(16)] fp16 -> block-contiguous 4KB slices
constexpr size_t OFF_H0   = 0;                                   // 1 MB  h ping
constexpr size_t OFF_CNT  = (size_t)1 << 20;                     // 4 KB  counters + inv flags
constexpr size_t OFF_H1   = ((size_t)1 << 20) + 4096;            // 1 MB  h pong
constexpr size_t OFF_BSUM = OFF_H1 + ((size_t)1 << 20);          // 16 KB b_ih+b_hh (fp32)
constexpr size_t OFF_WCAT = OFF_BSUM + 16384;                    // 9.4 MB fp16 [4096][1152]
constexpr size_t OFF_XT   = OFF_WCAT + (size_t)4096 * KTOT * 2;  // 33.4 MB fp16 [255][512][128]
}

__device__ __forceinline__ unsigned short f2h(float f) {
  _Float16 h = (_Float16)f;
  return __builtin_bit_cast(unsigned short, h);
}
__device__ __forceinline__ float h2f(unsigned short s) {
  return (float)__builtin_bit_cast(_Float16, s);
}

// ---------- prep 1: Wcat fp16 + bsum ----------
__global__ void prep_wcat(const float* __restrict__ Wih, const float* __restrict__ Whh,
                          const float* __restrict__ bih, const float* __restrict__ bhh,
                          char* __restrict__ ws) {
  if (blockIdx.x < 2304) {
    unsigned gid = blockIdx.x * 256 + threadIdx.x;
    unsigned row = gid / 144, cc = gid % 144;
    const float* src = (cc < 128) ? (Whh + (size_t)row * 1024 + (size_t)cc * 8)
                                  : (Wih + (size_t)row * 128 + (size_t)(cc - 128) * 8);
    ushort8 o;
#pragma unroll
    for (int j = 0; j < 8; j++) o[j] = f2h(src[j]);
    *(ushort8*)((unsigned short*)(ws + OFF_WCAT) + (size_t)row * KTOT + cc * 8) = o;
  } else {
    int i = (blockIdx.x - 2304) * 256 + threadIdx.x;
    ((float*)(ws + OFF_BSUM))[i] = bih[i] + bhh[i];
  }
}

// ---------- prep 2: xT[t][b][i] = fp16(x[b][i][t]) ----------
__global__ void prep_xt(const float* __restrict__ x, char* __restrict__ ws) {
  unsigned short* xT = (unsigned short*)(ws + OFF_XT);
  __shared__ unsigned short tile[128][72];
  const int b = blockIdx.x >> 2;
  const int t0 = (blockIdx.x & 3) * 64;
  const int wv = threadIdx.x >> 6, tl = threadIdx.x & 63;
  if (t0 + tl < 255) {
#pragma unroll
    for (int ii = 0; ii < 32; ii++) {
      int i = wv + ii * 4;
      tile[i][tl] = f2h(x[((size_t)b * 128 + i) * 256 + t0 + tl]);
    }
  }
  __syncthreads();
  const int tl2 = threadIdx.x >> 4, ic = threadIdx.x & 15;
#pragma unroll
  for (int pp = 0; pp < 4; pp++) {
    int tloc = pp * 16 + tl2;
    int t = t0 + tloc;
    if (t < 255) {
      ushort8 v;
#pragma unroll
      for (int j = 0; j < 8; j++) v[j] = tile[ic * 8 + j][tloc];
      *(ushort8*)&xT[((size_t)t * 512 + b) * 128 + ic * 8] = v;
    }
  }
}

// counted-vmcnt + barrier (T3/T4)
#define WAITBAR(N) do { \
    asm volatile("s_waitcnt vmcnt(" #N ") lgkmcnt(0)\n\ts_barrier" ::: "memory"); \
    __builtin_amdgcn_sched_barrier(0); \
  } while (0)

// ---------- persistent LSTM kernel ----------
// grid 256. GROUP = bid & 3 (XCD-ALIGNED: with round-robin bid%8 -> XCD, group g
// lands only on XCDs {g, g+4}; each XCD hosts ONE group -> exactly one L2 inv
// per XCD per step and 32 co-XCD blocks share every h line through L2).
// cblk = bid >> 2 (unit tile). 8 waves = 4K x 2N. Coherence: h write-through ->
// LLC always fresh; leader-elected buffer_inv before reads; relaxed release.
__global__ __launch_bounds__(512, 1) void lstm_persist(char* __restrict__ ws) {
  const unsigned short* __restrict__ wcat = (const unsigned short*)(ws + OFF_WCAT);
  const float* __restrict__ bsum = (const float*)(ws + OFF_BSUM);
  const unsigned short* __restrict__ xT = (const unsigned short*)(ws + OFF_XT);
  unsigned short* h0 = (unsigned short*)(ws + OFF_H0);
  unsigned short* h1 = (unsigned short*)(ws + OFF_H1);

  __shared__ __align__(16) unsigned short Ab[4][16384];   // 4 x 32KB chunk bufs / reduce scratch

  const int tid = threadIdx.x;
  const int lane = tid & 63;
  const int w = tid >> 6;
  const int wk = w & 3;           // K group (k-slice parity mod 4)
  const int wn = w >> 2;          // N half
  const int l15 = lane & 15, l4 = lane >> 4;
  const int gblk = blockIdx.x & 3;     // XCD-aligned group
  const int cblk = blockIdx.x >> 2;    // unit tile 0..63
  const int B0 = gblk * 128;
  const int U0 = cblk * 16;
  int* cntp = (int*)(ws + OFF_CNT) + gblk * 16;

  // per-(XCD, group) inv-leader flag cell (64B apart; zeroed by host memset)
  unsigned xcc;
  asm volatile("s_getreg_b32 %0, hwreg(HW_REG_XCC_ID)" : "=s"(xcc));
  int* flagp = (int*)(ws + OFF_CNT + 1024 + ((size_t)(xcc & 7) * 4 + gblk) * 64);

  // ---- weight fragments -> registers (col n = wn*32+nf*16+l15 -> unit n>>2, gate n&3) ----
  half8 bf[9][2];
  float bs[2];
#pragma unroll
  for (int nf = 0; nf < 2; nf++) {
    int u = wn * 8 + nf * 4 + (l15 >> 2);
    int R = (l15 & 3) * 1024 + U0 + u;          // PyTorch gate order i,f,g,o
    bs[nf] = bsum[R];
#pragma unroll
    for (int c = 0; c < 9; c++)
      bf[c][nf] = *(const half8*)&wcat[(size_t)R * KTOT + c * 128 + wk * 32 + l4 * 8];
  }
  const float bseed0 = (wk == 0) ? bs[0] : 0.f;
  const float bseed1 = (wk == 0) ? bs[1] : 0.f;

  // ---- staging: 32 slots of 1KB per 32KB chunk; slot s = w*4+i (wave-uniform LDS base) ----
  // LDS (row, c16) holds G(row, c16 ^ (row&7)); source pre-inverse-swizzled (rule #21).
  int hoffc[4], xoff[4];
#pragma unroll
  for (int i = 0; i < 4; i++) {
    int s = w * 4 + i;
    int row = s * 4 + (lane >> 4);
    int cg = (lane & 15) ^ (row & 7);
    hoffc[i] = (cg >> 1) * 2048 + row * 16 + (cg & 1) * 8;   // + c*16384 per chunk
    xoff[i] = (B0 + row) * 128 + cg * 8;
  }
  // A ds_read: row = m*16+l15, c16 = (wk*4+l4) ^ (l15&7)
  const int aBase = l15 * 256 + (((wk * 4 + l4) ^ (l15 & 7)) * 16);

  // reduce-exchange swizzle constants (writer side)
  int nb16[2], hn[2];
#pragma unroll
  for (int nf = 0; nf < 2; nf++) {
    int n = wn * 32 + nf * 16 + l15;
    nb16[nf] = n * 32;
    hn[nf] = (n ^ (n >> 3)) & 7;
  }
  // reader side: thread owns cells (rows 4*rfr..4*rfr+3, unit ucell)
  const int ucell = tid & 15;
  const int rfr = tid >> 4;
  int ra16[4];
#pragma unroll
  for (int g2 = 0; g2 < 4; g2++) {
    int n = 4 * ucell + g2;
    ra16[g2] = n * 32 + (rfr ^ ((n ^ (n >> 3)) & 7));
  }
  char* lds = (char*)&Ab[0][0];

  f4 acc[8][2];

// h loads: NORMAL caching -> L2-shared across the 32 co-XCD blocks of this group
#define STAGE_H(C, BUF) do { \
    _Pragma("unroll") \
    for (int i = 0; i < 4; i++) \
      __builtin_amdgcn_global_load_lds( \
          (const __attribute__((address_space(1))) void*)(hsrcg + hoffc[i] + (C) * 16384), \
          (__attribute__((address_space(3))) void*)((char*)&Ab[BUF][0] + (w * 4 + i) * 1024), \
          16, 0, 0); \
  } while (0)

#define STAGE_X() do { \
    _Pragma("unroll") \
    for (int i = 0; i < 4; i++) \
      __builtin_amdgcn_global_load_lds( \
          (const __attribute__((address_space(1))) void*)(xslab + xoff[i]), \
          (__attribute__((address_space(3))) void*)((char*)&Ab[3][0] + (w * 4 + i) * 1024), \
          16, 0, 0); \
  } while (0)

#define COMPUTE(C, BUF) do { \
    const char* _b = (const char*)&Ab[BUF][0] + aBase; \
    half8 a0 = *(const half8*)(_b); \
    half8 a1 = *(const half8*)(_b + 4096); \
    half8 a2 = *(const half8*)(_b + 8192); \
    half8 a3 = *(const half8*)(_b + 12288); \
    half8 a4 = *(const half8*)(_b + 16384); \
    half8 a5 = *(const half8*)(_b + 20480); \
    half8 a6 = *(const half8*)(_b + 24576); \
    half8 a7 = *(const half8*)(_b + 28672); \
    acc[0][0] = __builtin_amdgcn_mfma_f32_16x16x32_f16(a0, bf[C][0], acc[0][0], 0, 0, 0); \
    acc[0][1] = __builtin_amdgcn_mfma_f32_16x16x32_f16(a0, bf[C][1], acc[0][1], 0, 0, 0); \
    acc[1][0] = __builtin_amdgcn_mfma_f32_16x16x32_f16(a1, bf[C][0], acc[1][0], 0, 0, 0); \
    acc[1][1] = __builtin_amdgcn_mfma_f32_16x16x32_f16(a1, bf[C][1], acc[1][1], 0, 0, 0); \
    acc[2][0] = __builtin_amdgcn_mfma_f32_16x16x32_f16(a2, bf[C][0], acc[2][0], 0, 0, 0); \
    acc[2][1] = __builtin_amdgcn_mfma_f32_16x16x32_f16(a2, bf[C][1], acc[2][1], 0, 0, 0); \
    acc[3][0] = __builtin_amdgcn_mfma_f32_16x16x32_f16(a3, bf[C][0], acc[3][0], 0, 0, 0); \
    acc[3][1] = __builtin_amdgcn_mfma_f32_16x16x32_f16(a3, bf[C][1], acc[3][1], 0, 0, 0); \
    acc[4][0] = __builtin_amdgcn_mfma_f32_16x16x32_f16(a4, bf[C][0], acc[4][0], 0, 0, 0); \
    acc[4][1] = __builtin_amdgcn_mfma_f32_16x16x32_f16(a4, bf[C][1], acc[4][1], 0, 0, 0); \
    acc[5][0] = __builtin_amdgcn_mfma_f32_16x16x32_f16(a5, bf[C][0], acc[5][0], 0, 0, 0); \
    acc[5][1] = __builtin_amdgcn_mfma_f32_16x16x32_f16(a5, bf[C][1], acc[5][1], 0, 0, 0); \
    acc[6][0] = __builtin_amdgcn_mfma_f32_16x16x32_f16(a6, bf[C][0], acc[6][0], 0, 0, 0); \
    acc[6][1] = __builtin_amdgcn_mfma_f32_16x16x32_f16(a6, bf[C][1], acc[6][1], 0, 0, 0); \
    acc[7][0] = __builtin_amdgcn_mfma_f32_16x16x32_f16(a7, bf[C][0], acc[7][0], 0, 0, 0); \
    acc[7][1] = __builtin_amdgcn_mfma_f32_16x16x32_f16(a7, bf[C][1], acc[7][1], 0, 0, 0); \
  } while (0)

  f4 creg = {0.f, 0.f, 0.f, 0.f};   // 4 cells (rows 4*rfr+j, unit ucell)

#pragma unroll 1
  for (int t = 0; t < kSteps; t++) {
    const unsigned short* hsrcg = ((t & 1) ? h1 : h0) + gblk * 131072;
    unsigned short* hdst = (t & 1) ? h0 : h1;
    const unsigned short* xslab = xT + (size_t)t * (512 * 128);

#pragma unroll
    for (int m = 0; m < 8; m++) {
      acc[m][0] = (f4){bseed0, bseed0, bseed0, bseed0};
      acc[m][1] = (f4){bseed1, bseed1, bseed1, bseed1};
    }

    STAGE_X();                   // flies during the group-barrier wait

    if (tid == 0) {
      // 1) group rendezvous: all 64 blocks of this group finished step t-1
      int target = 64 * t;
      int guard = 1 << 18;
      while (guard--) {
        int c;
        asm volatile("global_load_dword %0, %1, off sc0 sc1\n\ts_waitcnt vmcnt(0)"
                     : "=v"(c) : "v"(cntp) : "memory");
        if (c >= target) break;
        __builtin_amdgcn_s_sleep(2);
      }
      // 2) per-(XCD,group) inv leader: with XCD-aligned groups this is exactly
      //    ONE full-L2 inv per XCD per step; 32 co-XCD blocks then share h via L2.
      //    Safe: nothing dirty anywhere (h write-through); inv after writers done,
      //    before any reader load (losers wait for flag).
      int expected = t;
      bool leader = __hip_atomic_compare_exchange_strong(
          flagp, &expected, -(t + 1), __ATOMIC_RELAXED, __ATOMIC_RELAXED,
          __HIP_MEMORY_SCOPE_AGENT);
      if (leader) {
        asm volatile("buffer_inv sc0 sc1\n\ts_waitcnt vmcnt(0)" ::: "memory");
        int done = t + 1;
        asm volatile("global_store_dword %0, %1, off sc0 sc1"
                     :: "v"(flagp), "v"(done) : "memory");
      } else {
        int g2 = 1 << 18;
        while (g2--) {
          int v;
          asm volatile("global_load_dword %0, %1, off sc0 sc1\n\ts_waitcnt vmcnt(0)"
                       : "=v"(v) : "v"(flagp) : "memory");
          if (v == t + 1) break;
          __builtin_amdgcn_s_sleep(1);
        }
        // own-CU L1 may hold this block's step t-2 h lines: cheap local inv
        asm volatile("buffer_inv sc0\n\ts_waitcnt vmcnt(0)" ::: "memory");
      }
    }
    __syncthreads();             // join; drains x staging (vmcnt 0)

    // r8-proven 2-deep schedule (8 loads in flight; overwrite >= 1 barrier after last read)
    STAGE_H(0, 0); STAGE_H(1, 1);
    COMPUTE(8, 3);                    // x contribution (buf3 resident)
    STAGE_H(2, 2);
    WAITBAR(8);  COMPUTE(0, 0);
    STAGE_H(3, 3);
    WAITBAR(8);  COMPUTE(1, 1);
    STAGE_H(4, 0);
    WAITBAR(8);  COMPUTE(2, 2);
    STAGE_H(5, 1);
    WAITBAR(8);  COMPUTE(3, 3);
    STAGE_H(6, 2);
    WAITBAR(8);  COMPUTE(4, 0);
    STAGE_H(7, 3);
    WAITBAR(8);  COMPUTE(5, 1);
    WAITBAR(4);  COMPUTE(6, 2);
    WAITBAR(0);  COMPUTE(7, 3);

    // ---- 4-way K reduction through LDS (128KB over bufs 0-3) ----
    asm volatile("s_waitcnt lgkmcnt(0)\n\ts_barrier" ::: "memory");  // staging reads done
#pragma unroll
    for (int m = 0; m < 8; m++)
#pragma unroll
      for (int nf = 0; nf < 2; nf++) {
        int rf = m * 4 + l4;
        *(f4*)(lds + (size_t)(wk * 2048 + nb16[nf] + (rf ^ hn[nf])) * 16) = acc[m][nf];
      }
    __syncthreads();
    {
      f4 gs[4];
#pragma unroll
      for (int g2 = 0; g2 < 4; g2++) {
        f4 v0 = *(const f4*)(lds + (size_t)ra16[g2] * 16);
        f4 v1 = *(const f4*)(lds + 32768 + (size_t)ra16[g2] * 16);
        f4 v2 = *(const f4*)(lds + 65536 + (size_t)ra16[g2] * 16);
        f4 v3 = *(const f4*)(lds + 98304 + (size_t)ra16[g2] * 16);
        gs[g2] = (v0 + v1) + (v2 + v3);
      }
      size_t hb = (size_t)((gblk * 64 + cblk) * 128 + rfr * 4) * 16 + ucell;
#pragma unroll
      for (int j = 0; j < 4; j++) {
        float ig = 1.f / (1.f + __expf(-gs[0][j]));
        float fg = 1.f / (1.f + __expf(-gs[1][j]));
        float gg = 2.f / (1.f + __expf(-2.f * gs[2][j])) - 1.f;
        float og = 1.f / (1.f + __expf(-gs[3][j]));
        float cn = fg * creg[j] + ig * gg;
        creg[j] = cn;
        float th = 2.f / (1.f + __expf(-2.f * cn)) - 1.f;
        // write-through to LLC: coherent across XCDs, leaves no dirty L2 line
        unsigned short* hp = hdst + hb + (size_t)j * 16;
        unsigned hv = f2h(og * th);
        asm volatile("global_store_short %0, %1, off sc0 sc1"
                     :: "v"(hp), "v"(hv) : "memory");
      }
    }
    __syncthreads();             // drains h stores (ack'd at LLC) + reduce reads
    if (tid == 0)                // RELAXED: no buffer_wbl2 (nothing dirty to flush)
      __hip_atomic_fetch_add(cntp, 1, __ATOMIC_RELAXED, __HIP_MEMORY_SCOPE_AGENT);
  }
#undef STAGE_H
#undef STAGE_X
#undef COMPUTE
}

// ---------- FC: out = h_last @ W_fc^T + b_fc ----------
__global__ void fc_kernel(const char* __restrict__ ws, const float* __restrict__ Wfc,
                          const float* __restrict__ bfc, float* __restrict__ out) {
  const unsigned short* h = (const unsigned short*)(ws + OFF_H1);  // t=254 writes h1
  int o = threadIdx.x & 127;
  int b = blockIdx.x * 2 + (threadIdx.x >> 7);
  const float* wrow = Wfc + (size_t)o * 1024;
  float acc = bfc[o];
  int gb = b >> 7, rb = b & 127;
#pragma unroll 4
  for (int k = 0; k < 1024; k += 8) {
    ushort8 hv = *(const ushort8*)&h[((size_t)(gb * 64 + (k >> 4)) * 128 + rb) * 16 + (k & 15)];
    f4 w0 = *(const f4*)&wrow[k];
    f4 w1 = *(const f4*)&wrow[k + 4];
#pragma unroll
    for (int j = 0; j < 4; j++) acc += h2f(hv[j]) * w0[j];
#pragma unroll
    for (int j = 0; j < 4; j++) acc += h2f(hv[4 + j]) * w1[j];
  }
  out[(size_t)b * 128 + o] = acc;
}

extern "C" void kernel_launch(void* const* d_in, const int* in_sizes, int n_in,
                              void* d_out, int out_size, void* d_ws, size_t ws_size,
                              hipStream_t stream) {
  const float* x   = (const float*)d_in[0];
  const float* Wih = (const float*)d_in[1];
  const float* Whh = (const float*)d_in[2];
  const float* bih = (const float*)d_in[3];
  const float* bhh = (const float*)d_in[4];
  const float* Wfc = (const float*)d_in[5];
  const float* bfc = (const float*)d_in[6];
  char* ws = (char*)d_ws;

  hipMemsetAsync(ws + OFF_H0, 0, ((size_t)1 << 20) + 4096, stream);
  prep_wcat<<<2320, 256, 0, stream>>>(Wih, Whh, bih, bhh, ws);
  prep_xt<<<2048, 256, 0, stream>>>(x, ws);
  lstm_persist<<<256, 512, 0, stream>>>(ws);
  fc_kernel<<<256, 256, 0, stream>>>(ws, Wfc, bfc, (float*)d_out);
}

// Round 13
// 2322.348 us; speedup vs baseline: 1.1543x; 1.0235x over previous
//
#include <hip/hip_runtime.h>
#include <stdint.h>
#include <stddef.h>

typedef __attribute__((ext_vector_type(8))) _Float16 half8;
typedef __attribute__((ext_vector_type(8))) unsigned short ushort8;
typedef __attribute__((ext_vector_type(4))) float f4;

namespace {
constexpr int kSteps = 255;   // reference iterates t = 0 .. T-2
constexpr int KTOT = 1152;    // 1024 (h) + 128 (x)

// workspace layout (bytes); total ~45 MB
// h layout: [group(8)][ub(32)][row(64)][u(32)] fp16 -> block-contiguous 4KB slices
constexpr size_t OFF_H0   = 0;                                   // 1 MB  h ping
constexpr size_t OFF_CNT  = (size_t)1 << 20;                     // 4 KB  counters(8x64B) + flags(64x32B)
constexpr size_t OFF_H1   = ((size_t)1 << 20) + 4096;            // 1 MB  h pong
constexpr size_t OFF_BSUM = OFF_H1 + ((size_t)1 << 20);          // 16 KB b_ih+b_hh (fp32)
constexpr size_t OFF_WCAT = OFF_BSUM + 16384;                    // 9.4 MB fp16 [4096][1152]
constexpr size_t OFF_XT   = OFF_WCAT + (size_t)4096 * KTOT * 2;  // 33.4 MB fp16 [255][512][128]
}

__device__ __forceinline__ unsigned short f2h(float f) {
  _Float16 h = (_Float16)f;
  return __builtin_bit_cast(unsigned short, h);
}
__device__ __forceinline__ float h2f(unsigned short s) {
  return (float)__builtin_bit_cast(_Float16, s);
}

// ---------- prep 1: Wcat fp16 + bsum ----------
__global__ void prep_wcat(const float* __restrict__ Wih, const float* __restrict__ Whh,
                          const float* __restrict__ bih, const float* __restrict__ bhh,
                          char* __restrict__ ws) {
  if (blockIdx.x < 2304) {
    unsigned gid = blockIdx.x * 256 + threadIdx.x;
    unsigned row = gid / 144, cc = gid % 144;
    const float* src = (cc < 128) ? (Whh + (size_t)row * 1024 + (size_t)cc * 8)
                                  : (Wih + (size_t)row * 128 + (size_t)(cc - 128) * 8);
    ushort8 o;
#pragma unroll
    for (int j = 0; j < 8; j++) o[j] = f2h(src[j]);
    *(ushort8*)((unsigned short*)(ws + OFF_WCAT) + (size_t)row * KTOT + cc * 8) = o;
  } else {
    int i = (blockIdx.x - 2304) * 256 + threadIdx.x;
    ((float*)(ws + OFF_BSUM))[i] = bih[i] + bhh[i];
  }
}

// ---------- prep 2: xT[t][b][i] = fp16(x[b][i][t]) ----------
__global__ void prep_xt(const float* __restrict__ x, char* __restrict__ ws) {
  unsigned short* xT = (unsigned short*)(ws + OFF_XT);
  __shared__ unsigned short tile[128][72];
  const int b = blockIdx.x >> 2;
  const int t0 = (blockIdx.x & 3) * 64;
  const int wv = threadIdx.x >> 6, tl = threadIdx.x & 63;
  if (t0 + tl < 255) {
#pragma unroll
    for (int ii = 0; ii < 32; ii++) {
      int i = wv + ii * 4;
      tile[i][tl] = f2h(x[((size_t)b * 128 + i) * 256 + t0 + tl]);
    }
  }
  __syncthreads();
  const int tl2 = threadIdx.x >> 4, ic = threadIdx.x & 15;
#pragma unroll
  for (int pp = 0; pp < 4; pp++) {
    int tloc = pp * 16 + tl2;
    int t = t0 + tloc;
    if (t < 255) {
      ushort8 v;
#pragma unroll
      for (int j = 0; j < 8; j++) v[j] = tile[ic * 8 + j][tloc];
      *(ushort8*)&xT[((size_t)t * 512 + b) * 128 + ic * 8] = v;
    }
  }
}

// counted-vmcnt + barrier (T3/T4)
#define WAITBAR(N) do { \
    asm volatile("s_waitcnt vmcnt(" #N ") lgkmcnt(0)\n\ts_barrier" ::: "memory"); \
    __builtin_amdgcn_sched_barrier(0); \
  } while (0)

// ---------- persistent LSTM kernel ----------
// grid 256 = 8 groups (64 rows, XCD-aligned: gblk = bid&7) x 32 unit-blocks (32 units).
// 8 waves = 4K x 2N; per-wave weights 288 halves = 144 VGPR (waves_per_eu pinned 2,2).
// Halves LDS reads / staging / L2 h-serve vs the 4x64 tiling (r12).
// Coherence (r12-proven): h write-through sc0 sc1 -> LLC; leader buffer_inv per
// (XCD,group); relaxed release; bounded bypass spin.
__global__ __launch_bounds__(512) __attribute__((amdgpu_waves_per_eu(2, 2)))
void lstm_persist(char* __restrict__ ws) {
  const unsigned short* __restrict__ wcat = (const unsigned short*)(ws + OFF_WCAT);
  const float* __restrict__ bsum = (const float*)(ws + OFF_BSUM);
  const unsigned short* __restrict__ xT = (const unsigned short*)(ws + OFF_XT);
  unsigned short* h0 = (unsigned short*)(ws + OFF_H0);
  unsigned short* h1 = (unsigned short*)(ws + OFF_H1);

  __shared__ __align__(16) unsigned short Ab[65536];   // 128KB: 4x16KB staging ring + reduce
  char* lds = (char*)&Ab[0];

  const int tid = threadIdx.x;
  const int lane = tid & 63;
  const int w = tid >> 6;
  const int wk = w & 3;           // K group (32-col slice of each 128-col chunk)
  const int wn = w >> 2;          // N half (64 of 128 gate cols)
  const int l15 = lane & 15, l4 = lane >> 4;
  const int gblk = blockIdx.x & 7;     // XCD-aligned group (round-robin bid%8 -> XCD)
  const int cblk = blockIdx.x >> 3;    // unit tile 0..31
  const int B0 = gblk * 64;
  const int U0 = cblk * 32;
  int* cntp = (int*)(ws + OFF_CNT) + gblk * 16;   // 8 counters, 64B apart

  unsigned xcc;
  asm volatile("s_getreg_b32 %0, hwreg(HW_REG_XCC_ID)" : "=s"(xcc));
  int* flagp = (int*)(ws + OFF_CNT + 512 + ((size_t)(xcc & 7) * 8 + gblk) * 32);

  // ---- weight fragments -> registers. col n = wn*64+nf*16+l15 = unit*4+gate ----
  half8 bf[9][4];   // [chunk][nf] = 36 half8 = 144 VGPR, persist whole kernel
  float bseed[4];
#pragma unroll
  for (int nf = 0; nf < 4; nf++) {
    int u = wn * 16 + nf * 4 + (l15 >> 2);
    int R = (l15 & 3) * 1024 + U0 + u;          // PyTorch gate order i,f,g,o
    float b = bsum[R];
    bseed[nf] = (wk == 0) ? b : 0.f;            // 4-way K reduce: one slice seeds bias
#pragma unroll
    for (int c = 0; c < 9; c++)
      bf[c][nf] = *(const half8*)&wcat[(size_t)R * KTOT + c * 128 + wk * 32 + l4 * 8];
  }

  // ---- staging: chunk 16KB = 16 slots of 1KB; slot s = w*2+i (wave-uniform base) ----
  // LDS (row, c16) holds G(row, c16 ^ (row&7)); source pre-inverse-swizzled (rule #21).
  int hoffc[2], xoff[2];
#pragma unroll
  for (int i = 0; i < 2; i++) {
    int s = w * 2 + i;
    int row = s * 4 + (lane >> 4);            // 0..63
    int cg = (lane & 15) ^ (row & 7);
    hoffc[i] = (cg >> 2) * 2048 + row * 32 + (cg & 3) * 8;   // elems; + c*8192 per chunk
    xoff[i] = (B0 + row) * 128 + cg * 8;
  }
  // A ds_read: row = m*16+l15 (m 0..3), slot = (wk*4+l4) ^ (l15&7)
  const int aBase = l15 * 256 + (((wk * 4 + l4) ^ (l15 & 7)) * 16);

  // reduce-exchange constants. writer: n = wn*64+nf*16+l15 (0..127), rf = m*4+l4 (0..15)
  int nb16[4], hn[4];
#pragma unroll
  for (int nf = 0; nf < 4; nf++) {
    int n = wn * 64 + nf * 16 + l15;
    nb16[nf] = n * 16;
    hn[nf] = (n ^ (n >> 3)) & 7;
  }
  // reader: thread owns (unit uu, row-quad rfr): 4 cells
  const int uu = tid & 31;
  const int rfr = tid >> 5;    // 0..15
  int ra16[4];
#pragma unroll
  for (int g2 = 0; g2 < 4; g2++) {
    int n = 4 * uu + g2;
    ra16[g2] = n * 16 + (rfr ^ ((n ^ (n >> 3)) & 7));
  }

  f4 acc[4][4];

#define STAGE_H(C, BUF) do { \
    _Pragma("unroll") \
    for (int i = 0; i < 2; i++) \
      __builtin_amdgcn_global_load_lds( \
          (const __attribute__((address_space(1))) void*)(hsrcg + hoffc[i] + (C) * 8192), \
          (__attribute__((address_space(3))) void*)(lds + (BUF) * 16384 + (w * 2 + i) * 1024), \
          16, 0, 0); \
  } while (0)

#define STAGE_X() do { \
    _Pragma("unroll") \
    for (int i = 0; i < 2; i++) \
      __builtin_amdgcn_global_load_lds( \
          (const __attribute__((address_space(1))) void*)(xslab + xoff[i]), \
          (__attribute__((address_space(3))) void*)(lds + 3 * 16384 + (w * 2 + i) * 1024), \
          16, 0, 0); \
  } while (0)

#define COMPUTE(C, BUF) do { \
    const char* _b = lds + (BUF) * 16384 + aBase; \
    half8 a0 = *(const half8*)(_b); \
    half8 a1 = *(const half8*)(_b + 4096); \
    half8 a2 = *(const half8*)(_b + 8192); \
    half8 a3 = *(const half8*)(_b + 12288); \
    acc[0][0] = __builtin_amdgcn_mfma_f32_16x16x32_f16(a0, bf[C][0], acc[0][0], 0, 0, 0); \
    acc[0][1] = __builtin_amdgcn_mfma_f32_16x16x32_f16(a0, bf[C][1], acc[0][1], 0, 0, 0); \
    acc[0][2] = __builtin_amdgcn_mfma_f32_16x16x32_f16(a0, bf[C][2], acc[0][2], 0, 0, 0); \
    acc[0][3] = __builtin_amdgcn_mfma_f32_16x16x32_f16(a0, bf[C][3], acc[0][3], 0, 0, 0); \
    acc[1][0] = __builtin_amdgcn_mfma_f32_16x16x32_f16(a1, bf[C][0], acc[1][0], 0, 0, 0); \
    acc[1][1] = __builtin_amdgcn_mfma_f32_16x16x32_f16(a1, bf[C][1], acc[1][1], 0, 0, 0); \
    acc[1][2] = __builtin_amdgcn_mfma_f32_16x16x32_f16(a1, bf[C][2], acc[1][2], 0, 0, 0); \
    acc[1][3] = __builtin_amdgcn_mfma_f32_16x16x32_f16(a1, bf[C][3], acc[1][3], 0, 0, 0); \
    acc[2][0] = __builtin_amdgcn_mfma_f32_16x16x32_f16(a2, bf[C][0], acc[2][0], 0, 0, 0); \
    acc[2][1] = __builtin_amdgcn_mfma_f32_16x16x32_f16(a2, bf[C][1], acc[2][1], 0, 0, 0); \
    acc[2][2] = __builtin_amdgcn_mfma_f32_16x16x32_f16(a2, bf[C][2], acc[2][2], 0, 0, 0); \
    acc[2][3] = __builtin_amdgcn_mfma_f32_16x16x32_f16(a2, bf[C][3], acc[2][3], 0, 0, 0); \
    acc[3][0] = __builtin_amdgcn_mfma_f32_16x16x32_f16(a3, bf[C][0], acc[3][0], 0, 0, 0); \
    acc[3][1] = __builtin_amdgcn_mfma_f32_16x16x32_f16(a3, bf[C][1], acc[3][1], 0, 0, 0); \
    acc[3][2] = __builtin_amdgcn_mfma_f32_16x16x32_f16(a3, bf[C][2], acc[3][2], 0, 0, 0); \
    acc[3][3] = __builtin_amdgcn_mfma_f32_16x16x32_f16(a3, bf[C][3], acc[3][3], 0, 0, 0); \
  } while (0)

  f4 creg = {0.f, 0.f, 0.f, 0.f};   // 4 cells (rows 4*rfr+j, unit uu)

#pragma unroll 1
  for (int t = 0; t < kSteps; t++) {
    const unsigned short* hsrcg = ((t & 1) ? h1 : h0) + gblk * 65536;
    unsigned short* hdst = (t & 1) ? h0 : h1;
    const unsigned short* xslab = xT + (size_t)t * (512 * 128);

#pragma unroll
    for (int m = 0; m < 4; m++)
#pragma unroll
      for (int nf = 0; nf < 4; nf++)
        acc[m][nf] = (f4){bseed[nf], bseed[nf], bseed[nf], bseed[nf]};

    STAGE_X();                   // flies during the group-barrier wait

    if (tid == 0) {
      // 1) group rendezvous: all 32 blocks of this group finished step t-1
      int target = 32 * t;
      int guard = 1 << 18;
      while (guard--) {
        int c;
        asm volatile("global_load_dword %0, %1, off sc0 sc1\n\ts_waitcnt vmcnt(0)"
                     : "=v"(c) : "v"(cntp) : "memory");
        if (c >= target) break;
        __builtin_amdgcn_s_sleep(2);
      }
      // 2) per-(XCD,group) inv leader: ONE full-L2 inv per XCD per step; 32
      //    co-XCD blocks then share h via L2. Nothing dirty anywhere (h is
      //    write-through); inv after writers done, before any reader load.
      int expected = t;
      bool leader = __hip_atomic_compare_exchange_strong(
          flagp, &expected, -(t + 1), __ATOMIC_RELAXED, __ATOMIC_RELAXED,
          __HIP_MEMORY_SCOPE_AGENT);
      if (leader) {
        asm volatile("buffer_inv sc0 sc1\n\ts_waitcnt vmcnt(0)" ::: "memory");
        int done = t + 1;
        asm volatile("global_store_dword %0, %1, off sc0 sc1"
                     :: "v"(flagp), "v"(done) : "memory");
      } else {
        int g2 = 1 << 18;
        while (g2--) {
          int v;
          asm volatile("global_load_dword %0, %1, off sc0 sc1\n\ts_waitcnt vmcnt(0)"
                       : "=v"(v) : "v"(flagp) : "memory");
          if (v == t + 1) break;
          __builtin_amdgcn_s_sleep(1);
        }
        asm volatile("buffer_inv sc0\n\ts_waitcnt vmcnt(0)" ::: "memory");  // own-L1 inv
      }
    }
    __syncthreads();             // join; drains x staging (vmcnt 0)

    // 2-deep schedule, 2 loads per stage (overwrite >= 1 WAITBAR after last reader)
    STAGE_H(0, 0); STAGE_H(1, 1);
    COMPUTE(8, 3);                    // x contribution (buf3 resident)
    STAGE_H(2, 2);
    WAITBAR(4);  COMPUTE(0, 0);
    STAGE_H(3, 3);
    WAITBAR(4);  COMPUTE(1, 1);
    STAGE_H(4, 0);
    WAITBAR(4);  COMPUTE(2, 2);
    STAGE_H(5, 1);
    WAITBAR(4);  COMPUTE(3, 3);
    STAGE_H(6, 2);
    WAITBAR(4);  COMPUTE(4, 0);
    STAGE_H(7, 3);
    WAITBAR(4);  COMPUTE(5, 1);
    WAITBAR(2);  COMPUTE(6, 2);
    WAITBAR(0);  COMPUTE(7, 3);

    // ---- 4-way K reduction through LDS (128KB) ----
    asm volatile("s_waitcnt lgkmcnt(0)\n\ts_barrier" ::: "memory");  // staging reads done
#pragma unroll
    for (int m = 0; m < 4; m++)
#pragma unroll
      for (int nf = 0; nf < 4; nf++) {
        int rf = m * 4 + l4;
        *(f4*)(lds + (size_t)(wk * 2048 + nb16[nf] + (rf ^ hn[nf])) * 16) = acc[m][nf];
      }
    __syncthreads();
    {
      f4 gs[4];
#pragma unroll
      for (int g2 = 0; g2 < 4; g2++) {
        f4 v0 = *(const f4*)(lds + (size_t)ra16[g2] * 16);
        f4 v1 = *(const f4*)(lds + 32768 + (size_t)ra16[g2] * 16);
        f4 v2 = *(const f4*)(lds + 65536 + (size_t)ra16[g2] * 16);
        f4 v3 = *(const f4*)(lds + 98304 + (size_t)ra16[g2] * 16);
        gs[g2] = (v0 + v1) + (v2 + v3);
      }
      size_t hb = (size_t)((gblk * 32 + cblk) * 64 + rfr * 4) * 32 + uu;
#pragma unroll
      for (int j = 0; j < 4; j++) {
        float ig = 1.f / (1.f + __expf(-gs[0][j]));
        float fg = 1.f / (1.f + __expf(-gs[1][j]));
        float gg = 2.f / (1.f + __expf(-2.f * gs[2][j])) - 1.f;
        float og = 1.f / (1.f + __expf(-gs[3][j]));
        float cn = fg * creg[j] + ig * gg;
        creg[j] = cn;
        float th = 2.f / (1.f + __expf(-2.f * cn)) - 1.f;
        // write-through to LLC: coherent across XCDs, leaves no dirty L2 line
        unsigned short* hp = hdst + hb + (size_t)j * 32;
        unsigned hv = f2h(og * th);
        asm volatile("global_store_short %0, %1, off sc0 sc1"
                     :: "v"(hp), "v"(hv) : "memory");
      }
    }
    __syncthreads();             // drains h stores (ack'd at LLC) + reduce reads
    if (tid == 0)                // RELAXED: no buffer_wbl2 (nothing dirty to flush)
      __hip_atomic_fetch_add(cntp, 1, __ATOMIC_RELAXED, __HIP_MEMORY_SCOPE_AGENT);
  }
#undef STAGE_H
#undef STAGE_X
#undef COMPUTE
}

// ---------- FC: out = h_last @ W_fc^T + b_fc ----------
__global__ void fc_kernel(const char* __restrict__ ws, const float* __restrict__ Wfc,
                          const float* __restrict__ bfc, float* __restrict__ out) {
  const unsigned short* h = (const unsigned short*)(ws + OFF_H1);  // t=254 writes h1
  int o = threadIdx.x & 127;
  int b = blockIdx.x * 2 + (threadIdx.x >> 7);
  const float* wrow = Wfc + (size_t)o * 1024;
  float acc = bfc[o];
  int gb = b >> 6, rb = b & 63;
#pragma unroll 4
  for (int k = 0; k < 1024; k += 8) {
    ushort8 hv = *(const ushort8*)&h[((size_t)(gb * 32 + (k >> 5)) * 64 + rb) * 32 + (k & 31)];
    f4 w0 = *(const f4*)&wrow[k];
    f4 w1 = *(const f4*)&wrow[k + 4];
#pragma unroll
    for (int j = 0; j < 4; j++) acc += h2f(hv[j]) * w0[j];
#pragma unroll
    for (int j = 0; j < 4; j++) acc += h2f(hv[4 + j]) * w1[j];
  }
  out[(size_t)b * 128 + o] = acc;
}

extern "C" void kernel_launch(void* const* d_in, const int* in_sizes, int n_in,
                              void* d_out, int out_size, void* d_ws, size_t ws_size,
                              hipStream_t stream) {
  const float* x   = (const float*)d_in[0];
  const float* Wih = (const float*)d_in[1];
  const float* Whh = (const float*)d_in[2];
  const float* bih = (const float*)d_in[3];
  const float* bhh = (const float*)d_in[4];
  const float* Wfc = (const float*)d_in[5];
  const float* bfc = (const float*)d_in[6];
  char* ws = (char*)d_ws;

  hipMemsetAsync(ws + OFF_H0, 0, ((size_t)1 << 20) + 4096, stream);
  prep_wcat<<<2320, 256, 0, stream>>>(Wih, Whh, bih, bhh, ws);
  prep_xt<<<2048, 256, 0, stream>>>(x, ws);
  lstm_persist<<<256, 512, 0, stream>>>(ws);
  fc_kernel<<<256, 256, 0, stream>>>(ws, Wfc, bfc, (float*)d_out);
}

// Round 14
// 2306.240 us; speedup vs baseline: 1.1624x; 1.0070x over previous
//
#include <hip/hip_runtime.h>
#include <stdint.h>
#include <stddef.h>

typedef __attribute__((ext_vector_type(8))) _Float16 half8;
typedef __attribute__((ext_vector_type(8))) unsigned short ushort8;
typedef __attribute__((ext_vector_type(4))) float f4;

namespace {
constexpr int kSteps = 255;   // reference iterates t = 0 .. T-2
constexpr int KTOT = 1152;    // 1024 (h) + 128 (x)

// workspace layout (bytes); total ~45 MB
// h layout: [group(8)][ub(32)][row(64)][u(32)] fp16 -> block-contiguous 4KB slices
constexpr size_t OFF_H0   = 0;                                   // 1 MB  h ping
constexpr size_t OFF_CNT  = (size_t)1 << 20;                     // 4 KB  counters(8x64B) + flags(64x32B)
constexpr size_t OFF_H1   = ((size_t)1 << 20) + 4096;            // 1 MB  h pong
constexpr size_t OFF_BSUM = OFF_H1 + ((size_t)1 << 20);          // 16 KB b_ih+b_hh (fp32)
constexpr size_t OFF_WCAT = OFF_BSUM + 16384;                    // 9.4 MB fp16 [4096][1152]
constexpr size_t OFF_XT   = OFF_WCAT + (size_t)4096 * KTOT * 2;  // 33.4 MB fp16 [255][512][128]
}

__device__ __forceinline__ unsigned short f2h(float f) {
  _Float16 h = (_Float16)f;
  return __builtin_bit_cast(unsigned short, h);
}
__device__ __forceinline__ float h2f(unsigned short s) {
  return (float)__builtin_bit_cast(_Float16, s);
}

// ---------- prep 1: Wcat fp16 + bsum ----------
__global__ void prep_wcat(const float* __restrict__ Wih, const float* __restrict__ Whh,
                          const float* __restrict__ bih, const float* __restrict__ bhh,
                          char* __restrict__ ws) {
  if (blockIdx.x < 2304) {
    unsigned gid = blockIdx.x * 256 + threadIdx.x;
    unsigned row = gid / 144, cc = gid % 144;
    const float* src = (cc < 128) ? (Whh + (size_t)row * 1024 + (size_t)cc * 8)
                                  : (Wih + (size_t)row * 128 + (size_t)(cc - 128) * 8);
    ushort8 o;
#pragma unroll
    for (int j = 0; j < 8; j++) o[j] = f2h(src[j]);
    *(ushort8*)((unsigned short*)(ws + OFF_WCAT) + (size_t)row * KTOT + cc * 8) = o;
  } else {
    int i = (blockIdx.x - 2304) * 256 + threadIdx.x;
    ((float*)(ws + OFF_BSUM))[i] = bih[i] + bhh[i];
  }
}

// ---------- prep 2: xT[t][b][i] = fp16(x[b][i][t]) ----------
__global__ void prep_xt(const float* __restrict__ x, char* __restrict__ ws) {
  unsigned short* xT = (unsigned short*)(ws + OFF_XT);
  __shared__ unsigned short tile[128][72];
  const int b = blockIdx.x >> 2;
  const int t0 = (blockIdx.x & 3) * 64;
  const int wv = threadIdx.x >> 6, tl = threadIdx.x & 63;
  if (t0 + tl < 255) {
#pragma unroll
    for (int ii = 0; ii < 32; ii++) {
      int i = wv + ii * 4;
      tile[i][tl] = f2h(x[((size_t)b * 128 + i) * 256 + t0 + tl]);
    }
  }
  __syncthreads();
  const int tl2 = threadIdx.x >> 4, ic = threadIdx.x & 15;
#pragma unroll
  for (int pp = 0; pp < 4; pp++) {
    int tloc = pp * 16 + tl2;
    int t = t0 + tloc;
    if (t < 255) {
      ushort8 v;
#pragma unroll
      for (int j = 0; j < 8; j++) v[j] = tile[ic * 8 + j][tloc];
      *(ushort8*)&xT[((size_t)t * 512 + b) * 128 + ic * 8] = v;
    }
  }
}

// counted-vmcnt + barrier (T3/T4)
#define WAITBAR(N) do { \
    asm volatile("s_waitcnt vmcnt(" #N ") lgkmcnt(0)\n\ts_barrier" ::: "memory"); \
    __builtin_amdgcn_sched_barrier(0); \
  } while (0)

// ---------- persistent LSTM kernel ----------
// grid 256 = 8 groups (64 rows, XCD-aligned: gblk = bid&7) x 32 unit-blocks (32 units).
// 8 waves = 4K x 2N. Depth-4 staging over 8 distinct 16KB buffers (no intra-step
// buffer reuse -> WAR-free), 2 chunks per barrier phase (7 barriers/step).
// Coherence: h write-through sc0 sc1 -> LLC; EARLY-CAS leader inv (overlapped
// with the rendezvous spin); relaxed release; bounded bypass polls.
__global__ __launch_bounds__(512) __attribute__((amdgpu_waves_per_eu(2, 2)))
void lstm_persist(char* __restrict__ ws) {
  const unsigned short* __restrict__ wcat = (const unsigned short*)(ws + OFF_WCAT);
  const float* __restrict__ bsum = (const float*)(ws + OFF_BSUM);
  const unsigned short* __restrict__ xT = (const unsigned short*)(ws + OFF_XT);
  unsigned short* h0 = (unsigned short*)(ws + OFF_H0);
  unsigned short* h1 = (unsigned short*)(ws + OFF_H1);

  __shared__ __align__(16) unsigned short Ab[65536];   // 128KB: 8x16KB chunk bufs / reduce
  char* lds = (char*)&Ab[0];

  const int tid = threadIdx.x;
  const int lane = tid & 63;
  const int w = tid >> 6;
  const int wk = w & 3;           // K group (32-col slice of each 128-col chunk)
  const int wn = w >> 2;          // N half (64 of 128 gate cols)
  const int l15 = lane & 15, l4 = lane >> 4;
  const int gblk = blockIdx.x & 7;     // XCD-aligned group (round-robin bid%8 -> XCD)
  const int cblk = blockIdx.x >> 3;    // unit tile 0..31
  const int B0 = gblk * 64;
  const int U0 = cblk * 32;
  int* cntp = (int*)(ws + OFF_CNT) + gblk * 16;   // 8 counters, 64B apart

  unsigned xcc;
  asm volatile("s_getreg_b32 %0, hwreg(HW_REG_XCC_ID)" : "=s"(xcc));
  int* flagp = (int*)(ws + OFF_CNT + 512 + ((size_t)(xcc & 7) * 8 + gblk) * 32);

  // ---- weight fragments -> registers. col n = wn*64+nf*16+l15 = unit*4+gate ----
  half8 bf[9][4];   // [chunk][nf] = 36 half8 = 144 regs, persist whole kernel
  float bseed[4];
#pragma unroll
  for (int nf = 0; nf < 4; nf++) {
    int u = wn * 16 + nf * 4 + (l15 >> 2);
    int R = (l15 & 3) * 1024 + U0 + u;          // PyTorch gate order i,f,g,o
    float b = bsum[R];
    bseed[nf] = (wk == 0) ? b : 0.f;            // 4-way K reduce: one slice seeds bias
#pragma unroll
    for (int c = 0; c < 9; c++)
      bf[c][nf] = *(const half8*)&wcat[(size_t)R * KTOT + c * 128 + wk * 32 + l4 * 8];
  }

  // ---- staging: chunk 16KB = 16 slots of 1KB; slot s = w*2+i (wave-uniform base) ----
  // LDS (row, c16) holds G(row, c16 ^ (row&7)); source pre-inverse-swizzled (rule #21).
  int hoffc[2], xoff[2];
#pragma unroll
  for (int i = 0; i < 2; i++) {
    int s = w * 2 + i;
    int row = s * 4 + (lane >> 4);            // 0..63
    int cg = (lane & 15) ^ (row & 7);
    hoffc[i] = (cg >> 2) * 2048 + row * 32 + (cg & 3) * 8;   // elems; + c*8192 per chunk
    xoff[i] = (B0 + row) * 128 + cg * 8;
  }
  // A ds_read: row = m*16+l15 (m 0..3), slot = (wk*4+l4) ^ (l15&7)
  const int aBase = l15 * 256 + (((wk * 4 + l4) ^ (l15 & 7)) * 16);

  // reduce-exchange constants. writer: n = wn*64+nf*16+l15 (0..127), rf = m*4+l4 (0..15)
  int nb16[4], hn[4];
#pragma unroll
  for (int nf = 0; nf < 4; nf++) {
    int n = wn * 64 + nf * 16 + l15;
    nb16[nf] = n * 16;
    hn[nf] = (n ^ (n >> 3)) & 7;
  }
  // reader: thread owns (unit uu, row-quad rfr): 4 cells
  const int uu = tid & 31;
  const int rfr = tid >> 5;    // 0..15
  int ra16[4];
#pragma unroll
  for (int g2 = 0; g2 < 4; g2++) {
    int n = 4 * uu + g2;
    ra16[g2] = n * 16 + (rfr ^ ((n ^ (n >> 3)) & 7));
  }

  f4 acc[4][4];

#define STAGE_H(C, BUF) do { \
    _Pragma("unroll") \
    for (int i = 0; i < 2; i++) \
      __builtin_amdgcn_global_load_lds( \
          (const __attribute__((address_space(1))) void*)(hsrcg + hoffc[i] + (C) * 8192), \
          (__attribute__((address_space(3))) void*)(lds + (BUF) * 16384 + (w * 2 + i) * 1024), \
          16, 0, 0); \
  } while (0)

#define STAGE_X() do { \
    _Pragma("unroll") \
    for (int i = 0; i < 2; i++) \
      __builtin_amdgcn_global_load_lds( \
          (const __attribute__((address_space(1))) void*)(xslab + xoff[i]), \
          (__attribute__((address_space(3))) void*)(lds + 7 * 16384 + (w * 2 + i) * 1024), \
          16, 0, 0); \
  } while (0)

#define COMPUTE(C, BUF) do { \
    const char* _b = lds + (BUF) * 16384 + aBase; \
    half8 a0 = *(const half8*)(_b); \
    half8 a1 = *(const half8*)(_b + 4096); \
    half8 a2 = *(const half8*)(_b + 8192); \
    half8 a3 = *(const half8*)(_b + 12288); \
    acc[0][0] = __builtin_amdgcn_mfma_f32_16x16x32_f16(a0, bf[C][0], acc[0][0], 0, 0, 0); \
    acc[0][1] = __builtin_amdgcn_mfma_f32_16x16x32_f16(a0, bf[C][1], acc[0][1], 0, 0, 0); \
    acc[0][2] = __builtin_amdgcn_mfma_f32_16x16x32_f16(a0, bf[C][2], acc[0][2], 0, 0, 0); \
    acc[0][3] = __builtin_amdgcn_mfma_f32_16x16x32_f16(a0, bf[C][3], acc[0][3], 0, 0, 0); \
    acc[1][0] = __builtin_amdgcn_mfma_f32_16x16x32_f16(a1, bf[C][0], acc[1][0], 0, 0, 0); \
    acc[1][1] = __builtin_amdgcn_mfma_f32_16x16x32_f16(a1, bf[C][1], acc[1][1], 0, 0, 0); \
    acc[1][2] = __builtin_amdgcn_mfma_f32_16x16x32_f16(a1, bf[C][2], acc[1][2], 0, 0, 0); \
    acc[1][3] = __builtin_amdgcn_mfma_f32_16x16x32_f16(a1, bf[C][3], acc[1][3], 0, 0, 0); \
    acc[2][0] = __builtin_amdgcn_mfma_f32_16x16x32_f16(a2, bf[C][0], acc[2][0], 0, 0, 0); \
    acc[2][1] = __builtin_amdgcn_mfma_f32_16x16x32_f16(a2, bf[C][1], acc[2][1], 0, 0, 0); \
    acc[2][2] = __builtin_amdgcn_mfma_f32_16x16x32_f16(a2, bf[C][2], acc[2][2], 0, 0, 0); \
    acc[2][3] = __builtin_amdgcn_mfma_f32_16x16x32_f16(a2, bf[C][3], acc[2][3], 0, 0, 0); \
    acc[3][0] = __builtin_amdgcn_mfma_f32_16x16x32_f16(a3, bf[C][0], acc[3][0], 0, 0, 0); \
    acc[3][1] = __builtin_amdgcn_mfma_f32_16x16x32_f16(a3, bf[C][1], acc[3][1], 0, 0, 0); \
    acc[3][2] = __builtin_amdgcn_mfma_f32_16x16x32_f16(a3, bf[C][2], acc[3][2], 0, 0, 0); \
    acc[3][3] = __builtin_amdgcn_mfma_f32_16x16x32_f16(a3, bf[C][3], acc[3][3], 0, 0, 0); \
  } while (0)

  f4 creg = {0.f, 0.f, 0.f, 0.f};   // 4 cells (rows 4*rfr+j, unit uu)

#pragma unroll 1
  for (int t = 0; t < kSteps; t++) {
    const unsigned short* hsrcg = ((t & 1) ? h1 : h0) + gblk * 65536;
    unsigned short* hdst = (t & 1) ? h0 : h1;
    const unsigned short* xslab = xT + (size_t)t * (512 * 128);

#pragma unroll
    for (int m = 0; m < 4; m++)
#pragma unroll
      for (int nf = 0; nf < 4; nf++)
        acc[m][nf] = (f4){bseed[nf], bseed[nf], bseed[nf], bseed[nf]};

    STAGE_X();                   // -> buf7; flies during the rendezvous wait

    if (tid == 0) {
      // EARLY leader election + inv: FIRST arriver of this (XCD,group) invs L2
      // while the rest of the group still finishes step t-1 -> inv latency is
      // off the critical path. Safe: nothing is ever dirty (h write-through,
      // stores don't allocate L2); stale P-lines date from epoch t-2, whose
      // reads ended before anyone entered t-1; losers gate reads on the flag.
      int expected = t;
      bool leader = __hip_atomic_compare_exchange_strong(
          flagp, &expected, -(t + 1), __ATOMIC_RELAXED, __ATOMIC_RELAXED,
          __HIP_MEMORY_SCOPE_AGENT);
      if (leader) {
        asm volatile("buffer_inv sc0 sc1\n\ts_waitcnt vmcnt(0)" ::: "memory");
        int done = t + 1;
        asm volatile("global_store_dword %0, %1, off sc0 sc1"
                     :: "v"(flagp), "v"(done) : "memory");
      }
      // group rendezvous: all 32 blocks of this group finished step t-1
      int target = 32 * t;
      int guard = 1 << 18;
      while (guard--) {
        int c;
        asm volatile("global_load_dword %0, %1, off sc0 sc1\n\ts_waitcnt vmcnt(0)"
                     : "=v"(c) : "v"(cntp) : "memory");
        if (c >= target) break;
        __builtin_amdgcn_s_sleep(1);
      }
      if (!leader) {
        int g2 = 1 << 18;
        while (g2--) {            // leader published flag before its spin -> ~no wait
          int v;
          asm volatile("global_load_dword %0, %1, off sc0 sc1\n\ts_waitcnt vmcnt(0)"
                       : "=v"(v) : "v"(flagp) : "memory");
          if (v == t + 1) break;
          __builtin_amdgcn_s_sleep(1);
        }
        asm volatile("buffer_inv sc0\n\ts_waitcnt vmcnt(0)" ::: "memory");  // own-L1 inv
      }
    }
    __syncthreads();             // join; drains x staging (vmcnt 0)

    // depth-4, 8 distinct buffers, 2 chunks per phase (no buffer reuse in-step)
    STAGE_H(0, 0); STAGE_H(1, 1); STAGE_H(2, 2); STAGE_H(3, 3);   // 8 loads
    COMPUTE(8, 7);                    // x contribution while chunks 0-3 fly
    STAGE_H(4, 4); STAGE_H(5, 5);     // 12 in flight
    WAITBAR(8);  COMPUTE(0, 0); COMPUTE(1, 1);
    STAGE_H(6, 6); STAGE_H(7, 7);     // 12 in flight
    WAITBAR(8);  COMPUTE(2, 2); COMPUTE(3, 3);
    WAITBAR(4);  COMPUTE(4, 4); COMPUTE(5, 5);
    WAITBAR(0);  COMPUTE(6, 6); COMPUTE(7, 7);

    // ---- 4-way K reduction through LDS (128KB, all bufs free now) ----
    asm volatile("s_waitcnt lgkmcnt(0)\n\ts_barrier" ::: "memory");  // staging reads done
#pragma unroll
    for (int m = 0; m < 4; m++)
#pragma unroll
      for (int nf = 0; nf < 4; nf++) {
        int rf = m * 4 + l4;
        *(f4*)(lds + (size_t)(wk * 2048 + nb16[nf] + (rf ^ hn[nf])) * 16) = acc[m][nf];
      }
    __syncthreads();
    {
      f4 gs[4];
#pragma unroll
      for (int g2 = 0; g2 < 4; g2++) {
        f4 v0 = *(const f4*)(lds + (size_t)ra16[g2] * 16);
        f4 v1 = *(const f4*)(lds + 32768 + (size_t)ra16[g2] * 16);
        f4 v2 = *(const f4*)(lds + 65536 + (size_t)ra16[g2] * 16);
        f4 v3 = *(const f4*)(lds + 98304 + (size_t)ra16[g2] * 16);
        gs[g2] = (v0 + v1) + (v2 + v3);
      }
      size_t hb = (size_t)((gblk * 32 + cblk) * 64 + rfr * 4) * 32 + uu;
#pragma unroll
      for (int j = 0; j < 4; j++) {
        float ig = 1.f / (1.f + __expf(-gs[0][j]));
        float fg = 1.f / (1.f + __expf(-gs[1][j]));
        float gg = 2.f / (1.f + __expf(-2.f * gs[2][j])) - 1.f;
        float og = 1.f / (1.f + __expf(-gs[3][j]));
        float cn = fg * creg[j] + ig * gg;
        creg[j] = cn;
        float th = 2.f / (1.f + __expf(-2.f * cn)) - 1.f;
        // write-through to LLC: coherent across XCDs, leaves no dirty L2 line
        unsigned short* hp = hdst + hb + (size_t)j * 32;
        unsigned hv = f2h(og * th);
        asm volatile("global_store_short %0, %1, off sc0 sc1"
                     :: "v"(hp), "v"(hv) : "memory");
      }
    }
    __syncthreads();             // drains h stores (ack'd at LLC) + reduce reads
    if (tid == 0)                // RELAXED: no buffer_wbl2 (nothing dirty to flush)
      __hip_atomic_fetch_add(cntp, 1, __ATOMIC_RELAXED, __HIP_MEMORY_SCOPE_AGENT);
  }
#undef STAGE_H
#undef STAGE_X
#undef COMPUTE
}

// ---------- FC: out = h_last @ W_fc^T + b_fc ----------
__global__ void fc_kernel(const char* __restrict__ ws, const float* __restrict__ Wfc,
                          const float* __restrict__ bfc, float* __restrict__ out) {
  const unsigned short* h = (const unsigned short*)(ws + OFF_H1);  // t=254 writes h1
  int o = threadIdx.x & 127;
  int b = blockIdx.x * 2 + (threadIdx.x >> 7);
  const float* wrow = Wfc + (size_t)o * 1024;
  float acc = bfc[o];
  int gb = b >> 6, rb = b & 63;
#pragma unroll 4
  for (int k = 0; k < 1024; k += 8) {
    ushort8 hv = *(const ushort8*)&h[((size_t)(gb * 32 + (k >> 5)) * 64 + rb) * 32 + (k & 31)];
    f4 w0 = *(const f4*)&wrow[k];
    f4 w1 = *(const f4*)&wrow[k + 4];
#pragma unroll
    for (int j = 0; j < 4; j++) acc += h2f(hv[j]) * w0[j];
#pragma unroll
    for (int j = 0; j < 4; j++) acc += h2f(hv[4 + j]) * w1[j];
  }
  out[(size_t)b * 128 + o] = acc;
}

extern "C" void kernel_launch(void* const* d_in, const int* in_sizes, int n_in,
                              void* d_out, int out_size, void* d_ws, size_t ws_size,
                              hipStream_t stream) {
  const float* x   = (const float*)d_in[0];
  const float* Wih = (const float*)d_in[1];
  const float* Whh = (const float*)d_in[2];
  const float* bih = (const float*)d_in[3];
  const float* bhh = (const float*)d_in[4];
  const float* Wfc = (const float*)d_in[5];
  const float* bfc = (const float*)d_in[6];
  char* ws = (char*)d_ws;

  hipMemsetAsync(ws + OFF_H0, 0, ((size_t)1 << 20) + 4096, stream);
  prep_wcat<<<2320, 256, 0, stream>>>(Wih, Whh, bih, bhh, ws);
  prep_xt<<<2048, 256, 0, stream>>>(x, ws);
  lstm_persist<<<256, 512, 0, stream>>>(ws);
  fc_kernel<<<256, 256, 0, stream>>>(ws, Wfc, bfc, (float*)d_out);
}

// Round 15
// 1912.858 us; speedup vs baseline: 1.4014x; 1.2057x over previous
//
#include <hip/hip_runtime.h>
#include <stdint.h>
#include <stddef.h>

typedef __attribute__((ext_vector_type(8))) _Float16 half8;
typedef __attribute__((ext_vector_type(8))) unsigned short ushort8;
typedef __attribute__((ext_vector_type(4))) float f4;
typedef __attribute__((ext_vector_type(2))) float f2;

#define AS1 __attribute__((address_space(1)))
#define AS3 __attribute__((address_space(3)))

namespace {
constexpr int kSteps = 255;   // reference iterates t = 0 .. T-2
constexpr int KTOT = 1152;    // 1024 (h) + 128 (x)

// workspace layout (bytes); total ~45 MB
// h layout: [group(16)][ub(32)][row(32)][u(32)] fp16 -> 2KB block slices
constexpr size_t OFF_H0   = 0;                                   // 1 MB  h ping
constexpr size_t OFF_CNT  = (size_t)1 << 20;                     // 4 KB  counters (16 x 64B)
constexpr size_t OFF_H1   = ((size_t)1 << 20) + 4096;            // 1 MB  h pong
constexpr size_t OFF_BSUM = OFF_H1 + ((size_t)1 << 20);          // 16 KB b_ih+b_hh (fp32)
constexpr size_t OFF_WCAT = OFF_BSUM + 16384;                    // 9.4 MB fp16 [4096][1152]
constexpr size_t OFF_XT   = OFF_WCAT + (size_t)4096 * KTOT * 2;  // 33.4 MB fp16 [255][512][128]
}

__device__ __forceinline__ unsigned short f2h(float f) {
  _Float16 h = (_Float16)f;
  return __builtin_bit_cast(unsigned short, h);
}
__device__ __forceinline__ float h2f(unsigned short s) {
  return (float)__builtin_bit_cast(_Float16, s);
}

// ---------- prep 1: Wcat fp16 + bsum ----------
__global__ void prep_wcat(const float* __restrict__ Wih, const float* __restrict__ Whh,
                          const float* __restrict__ bih, const float* __restrict__ bhh,
                          char* __restrict__ ws) {
  if (blockIdx.x < 2304) {
    unsigned gid = blockIdx.x * 256 + threadIdx.x;
    unsigned row = gid / 144, cc = gid % 144;
    const float* src = (cc < 128) ? (Whh + (size_t)row * 1024 + (size_t)cc * 8)
                                  : (Wih + (size_t)row * 128 + (size_t)(cc - 128) * 8);
    ushort8 o;
#pragma unroll
    for (int j = 0; j < 8; j++) o[j] = f2h(src[j]);
    *(ushort8*)((unsigned short*)(ws + OFF_WCAT) + (size_t)row * KTOT + cc * 8) = o;
  } else {
    int i = (blockIdx.x - 2304) * 256 + threadIdx.x;
    ((float*)(ws + OFF_BSUM))[i] = bih[i] + bhh[i];
  }
}

// ---------- prep 2: xT[t][b][i] = fp16(x[b][i][t]) ----------
__global__ void prep_xt(const float* __restrict__ x, char* __restrict__ ws) {
  unsigned short* xT = (unsigned short*)(ws + OFF_XT);
  __shared__ unsigned short tile[128][72];
  const int b = blockIdx.x >> 2;
  const int t0 = (blockIdx.x & 3) * 64;
  const int wv = threadIdx.x >> 6, tl = threadIdx.x & 63;
  if (t0 + tl < 255) {
#pragma unroll
    for (int ii = 0; ii < 32; ii++) {
      int i = wv + ii * 4;
      tile[i][tl] = f2h(x[((size_t)b * 128 + i) * 256 + t0 + tl]);
    }
  }
  __syncthreads();
  const int tl2 = threadIdx.x >> 4, ic = threadIdx.x & 15;
#pragma unroll
  for (int pp = 0; pp < 4; pp++) {
    int tloc = pp * 16 + tl2;
    int t = t0 + tloc;
    if (t < 255) {
      ushort8 v;
#pragma unroll
      for (int j = 0; j < 8; j++) v[j] = tile[ic * 8 + j][tloc];
      *(ushort8*)&xT[((size_t)t * 512 + b) * 128 + ic * 8] = v;
    }
  }
}

// counted-vmcnt + barrier (T3/T4)
#define WAITBAR(N) do { \
    asm volatile("s_waitcnt vmcnt(" #N ") lgkmcnt(0)\n\ts_barrier" ::: "memory"); \
    __builtin_amdgcn_sched_barrier(0); \
  } while (0)

// ---------- persistent LSTM kernel: DUAL-CHAIN ----------
// grid 256 = (bid&7) -> chains' groups {g, g+8} (both XCD-aligned), bid>>3 -> 32-unit tile.
// 16 groups x 32 rows; per block: 2 independent recurrences sharing the same weight regs.
// Chain interleave A,B,A,B...: each chain's rendezvous has had a full other-chain step
// (~3us) since its last release -> spin finds counter already satisfied (latency hidden).
// Coherence (r8-proven, no inv): h stores write-through sc0 sc1 (update LLC + L2);
// h loads aux=1 (SC0 L1-bypass, L2-cached); relaxed release after vmcnt(0) drain.
__global__ __launch_bounds__(512) __attribute__((amdgpu_waves_per_eu(2, 2)))
void lstm_persist(char* __restrict__ ws) {
  const unsigned short* __restrict__ wcat = (const unsigned short*)(ws + OFF_WCAT);
  const float* __restrict__ bsum = (const float*)(ws + OFF_BSUM);
  const unsigned short* __restrict__ xT = (const unsigned short*)(ws + OFF_XT);
  unsigned short* h0 = (unsigned short*)(ws + OFF_H0);
  unsigned short* h1 = (unsigned short*)(ws + OFF_H1);

  __shared__ __align__(16) char lds[131072];   // 2 rings x (8 bufs x 8KB); exchange reuses ring

  const int tid = threadIdx.x;
  const int lane = tid & 63;
  const int w = tid >> 6;
  const int wk = w & 3;           // K slice (32 cols of each 128-col chunk)
  const int wn = w >> 2;          // N half (64 of 128 gate cols)
  const int l15 = lane & 15, l4 = lane >> 4;
  const int gA = blockIdx.x & 7;       // chain A group (XCD-aligned)
  const int gB = gA + 8;               // chain B group (same XCD)
  const int cblk = blockIdx.x >> 3;    // unit tile 0..31
  const int U0 = cblk * 32;
  int* cntA = (int*)(ws + OFF_CNT) + gA * 16;
  int* cntB = (int*)(ws + OFF_CNT) + gB * 16;

  // ---- weight fragments -> registers. col n = wn*64+nf*16+l15 = unit*4+gate ----
  half8 bf[9][4];   // 144 regs, shared by both chains
  float bseed[4];
#pragma unroll
  for (int nf = 0; nf < 4; nf++) {
    int u = wn * 16 + nf * 4 + (l15 >> 2);
    int R = (l15 & 3) * 1024 + U0 + u;          // PyTorch gate order i,f,g,o
    float b = bsum[R];
    bseed[nf] = (wk == 0) ? b : 0.f;            // 4-way K reduce: one slice seeds bias
#pragma unroll
    for (int c = 0; c < 9; c++)
      bf[c][nf] = *(const half8*)&wcat[(size_t)R * KTOT + c * 128 + wk * 32 + l4 * 8];
  }

  // ---- staging: chunk 8KB = 8 slots of 1KB; slot = w (1 load/wave/chunk) ----
  // LDS (row, c16) holds G(row, c16 ^ (row&7)); source pre-inverse-swizzled (rule #21).
  const int srow = w * 4 + (lane >> 4);          // 0..31
  const int scg = (lane & 15) ^ (srow & 7);
  const int hoff1 = (scg >> 2) * 1024 + srow * 32 + (scg & 3) * 8;   // + c*4096 per chunk
  const int xoA = (gA * 32 + srow) * 128 + scg * 8;
  const int xoB = (gB * 32 + srow) * 128 + scg * 8;
  // A ds_read: row = m*16+l15, c16 = (wk*4+l4) ^ (l15&7); a1 at +4096 (m=1)
  const int aBase = l15 * 256 + (((wk * 4 + l4) ^ (l15 & 7)) * 16);

  // exchange constants. writer: n = wn*64+nf*16+l15 (0..127), rf = m*4+l4 (0..7)
  int nb8[4], hnw[4];
#pragma unroll
  for (int nf = 0; nf < 4; nf++) {
    int n = wn * 64 + nf * 16 + l15;
    nb8[nf] = n * 8;
    hnw[nf] = (n ^ (n >> 3)) & 7;
  }
  // reader: thread owns (unit uu, rows qr*4+hi*2 .. +1); float2 reads per slice
  const int uu = tid & 31;
  const int qr = (tid >> 5) & 7;
  const int hi = (tid >> 8) & 1;
  int ro2[4];
#pragma unroll
  for (int g2 = 0; g2 < 4; g2++) {
    int n = 4 * uu + g2;
    ro2[g2] = (n * 8 + (qr ^ ((n ^ (n >> 3)) & 7))) * 16 + hi * 8;
  }
  const size_t hbA = ((size_t)(gA * 32 + cblk) * 32 + (qr * 4 + hi * 2)) * 32 + uu;
  const size_t hbB = ((size_t)(gB * 32 + cblk) * 32 + (qr * 4 + hi * 2)) * 32 + uu;

  f4 acc[2][4];
  float cA0 = 0.f, cA1 = 0.f, cB0 = 0.f, cB1 = 0.f;   // c-state, 2 cells per chain

#define STG(HS, C, RB, BUF) \
  __builtin_amdgcn_global_load_lds( \
      (const AS1 void*)((HS) + hoff1 + (C) * 4096), \
      (AS3 void*)(lds + (RB) + (BUF) * 8192 + w * 1024), 16, 0, 1)

#define CMP(C, RB, BUF) do { \
    const char* _b = lds + (RB) + (BUF) * 8192 + aBase; \
    half8 a0 = *(const half8*)(_b); \
    half8 a1 = *(const half8*)(_b + 4096); \
    acc[0][0] = __builtin_amdgcn_mfma_f32_16x16x32_f16(a0, bf[C][0], acc[0][0], 0, 0, 0); \
    acc[0][1] = __builtin_amdgcn_mfma_f32_16x16x32_f16(a0, bf[C][1], acc[0][1], 0, 0, 0); \
    acc[0][2] = __builtin_amdgcn_mfma_f32_16x16x32_f16(a0, bf[C][2], acc[0][2], 0, 0, 0); \
    acc[0][3] = __builtin_amdgcn_mfma_f32_16x16x32_f16(a0, bf[C][3], acc[0][3], 0, 0, 0); \
    acc[1][0] = __builtin_amdgcn_mfma_f32_16x16x32_f16(a1, bf[C][0], acc[1][0], 0, 0, 0); \
    acc[1][1] = __builtin_amdgcn_mfma_f32_16x16x32_f16(a1, bf[C][1], acc[1][1], 0, 0, 0); \
    acc[1][2] = __builtin_amdgcn_mfma_f32_16x16x32_f16(a1, bf[C][2], acc[1][2], 0, 0, 0); \
    acc[1][3] = __builtin_amdgcn_mfma_f32_16x16x32_f16(a1, bf[C][3], acc[1][3], 0, 0, 0); \
  } while (0)

// one full chain step: spin -> stage/compute -> reduce -> activate -> store -> release
#define CHAIN_STEP(HSRCG, HDST, HB, XSLAB, XO, CNTP, RB, C0, C1, TGT) do { \
    _Pragma("unroll") \
    for (int m = 0; m < 2; m++) \
      _Pragma("unroll") \
      for (int nf = 0; nf < 4; nf++) \
        acc[m][nf] = (f4){bseed[nf], bseed[nf], bseed[nf], bseed[nf]}; \
    __builtin_amdgcn_global_load_lds((const AS1 void*)((XSLAB) + (XO)), \
        (AS3 void*)(lds + (RB) + 7 * 8192 + w * 1024), 16, 0, 0); \
    if (tid == 0) { \
      int guard = 1 << 18; \
      while (guard--) { \
        int c; \
        asm volatile("global_load_dword %0, %1, off sc0 sc1\n\ts_waitcnt vmcnt(0)" \
                     : "=v"(c) : "v"(CNTP) : "memory"); \
        if (c >= (TGT)) break; \
        __builtin_amdgcn_s_sleep(1); \
      } \
    } \
    __syncthreads(); \
    STG(HSRCG, 0, RB, 0); STG(HSRCG, 1, RB, 1); STG(HSRCG, 2, RB, 2); STG(HSRCG, 3, RB, 3); \
    CMP(8, RB, 7); \
    STG(HSRCG, 4, RB, 4); STG(HSRCG, 5, RB, 5); \
    WAITBAR(4); CMP(0, RB, 0); CMP(1, RB, 1); \
    STG(HSRCG, 6, RB, 6); STG(HSRCG, 7, RB, 7); \
    WAITBAR(4); CMP(2, RB, 2); CMP(3, RB, 3); \
    WAITBAR(2); CMP(4, RB, 4); CMP(5, RB, 5); \
    WAITBAR(0); CMP(6, RB, 6); CMP(7, RB, 7); \
    asm volatile("s_waitcnt lgkmcnt(0)\n\ts_barrier" ::: "memory"); \
    _Pragma("unroll") \
    for (int m = 0; m < 2; m++) \
      _Pragma("unroll") \
      for (int nf = 0; nf < 4; nf++) { \
        int rf = m * 4 + l4; \
        *(f4*)(lds + (RB) + wk * 16384 + (size_t)(nb8[nf] + (rf ^ hnw[nf])) * 16) = acc[m][nf]; \
      } \
    __syncthreads(); \
    { \
      f2 gsv[4]; \
      _Pragma("unroll") \
      for (int g2 = 0; g2 < 4; g2++) { \
        f2 s0 = *(const f2*)(lds + (RB) + ro2[g2]); \
        f2 s1 = *(const f2*)(lds + (RB) + 16384 + ro2[g2]); \
        f2 s2 = *(const f2*)(lds + (RB) + 32768 + ro2[g2]); \
        f2 s3 = *(const f2*)(lds + (RB) + 49152 + ro2[g2]); \
        gsv[g2] = (s0 + s1) + (s2 + s3); \
      } \
      float ig0 = 1.f / (1.f + __expf(-gsv[0][0])); \
      float fg0 = 1.f / (1.f + __expf(-gsv[1][0])); \
      float gg0 = 2.f / (1.f + __expf(-2.f * gsv[2][0])) - 1.f; \
      float og0 = 1.f / (1.f + __expf(-gsv[3][0])); \
      float cn0 = fg0 * (C0) + ig0 * gg0; \
      (C0) = cn0; \
      float th0 = 2.f / (1.f + __expf(-2.f * cn0)) - 1.f; \
      unsigned short* hp0 = (HDST) + (HB); \
      unsigned hv0 = f2h(og0 * th0); \
      asm volatile("global_store_short %0, %1, off sc0 sc1" :: "v"(hp0), "v"(hv0) : "memory"); \
      float ig1 = 1.f / (1.f + __expf(-gsv[0][1])); \
      float fg1 = 1.f / (1.f + __expf(-gsv[1][1])); \
      float gg1 = 2.f / (1.f + __expf(-2.f * gsv[2][1])) - 1.f; \
      float og1 = 1.f / (1.f + __expf(-gsv[3][1])); \
      float cn1 = fg1 * (C1) + ig1 * gg1; \
      (C1) = cn1; \
      float th1 = 2.f / (1.f + __expf(-2.f * cn1)) - 1.f; \
      unsigned short* hp1 = (HDST) + (HB) + 32; \
      unsigned hv1 = f2h(og1 * th1); \
      asm volatile("global_store_short %0, %1, off sc0 sc1" :: "v"(hp1), "v"(hv1) : "memory"); \
    } \
    __syncthreads(); /* drains h stores (vmcnt 0, ack'd at coherence pt) + exch reads */ \
    if (tid == 0) \
      __hip_atomic_fetch_add(CNTP, 1, __ATOMIC_RELAXED, __HIP_MEMORY_SCOPE_AGENT); \
  } while (0)

#pragma unroll 1
  for (int t = 0; t < kSteps; t++) {
    const unsigned short* hsrc = (t & 1) ? h1 : h0;
    unsigned short* hdst = (t & 1) ? h0 : h1;
    const unsigned short* xslab = xT + (size_t)t * (512 * 128);
    const int tgt = 32 * t;

    // chain A (group gA): its release for t-1 happened one full B-step ago -> spin ~instant
    CHAIN_STEP(hsrc + gA * 32768, hdst, hbA, xslab, xoA, cntA, 0, cA0, cA1, tgt);
    // chain B (group gB): overlapped by A's compute in the same way
    CHAIN_STEP(hsrc + gB * 32768, hdst, hbB, xslab, xoB, cntB, 65536, cB0, cB1, tgt);
  }
#undef CHAIN_STEP
#undef CMP
#undef STG
}

// ---------- FC: out = h_last @ W_fc^T + b_fc ----------
__global__ void fc_kernel(const char* __restrict__ ws, const float* __restrict__ Wfc,
                          const float* __restrict__ bfc, float* __restrict__ out) {
  const unsigned short* h = (const unsigned short*)(ws + OFF_H1);  // t=254 writes h1
  int o = threadIdx.x & 127;
  int b = blockIdx.x * 2 + (threadIdx.x >> 7);
  const float* wrow = Wfc + (size_t)o * 1024;
  float acc = bfc[o];
  int gb = b >> 5, rb = b & 31;
#pragma unroll 4
  for (int k = 0; k < 1024; k += 8) {
    ushort8 hv = *(const ushort8*)&h[(((size_t)(gb * 32 + (k >> 5)) * 32 + rb) * 32) + (k & 31)];
    f4 w0 = *(const f4*)&wrow[k];
    f4 w1 = *(const f4*)&wrow[k + 4];
#pragma unroll
    for (int j = 0; j < 4; j++) acc += h2f(hv[j]) * w0[j];
#pragma unroll
    for (int j = 0; j < 4; j++) acc += h2f(hv[4 + j]) * w1[j];
  }
  out[(size_t)b * 128 + o] = acc;
}

extern "C" void kernel_launch(void* const* d_in, const int* in_sizes, int n_in,
                              void* d_out, int out_size, void* d_ws, size_t ws_size,
                              hipStream_t stream) {
  const float* x   = (const float*)d_in[0];
  const float* Wih = (const float*)d_in[1];
  const float* Whh = (const float*)d_in[2];
  const float* bih = (const float*)d_in[3];
  const float* bhh = (const float*)d_in[4];
  const float* Wfc = (const float*)d_in[5];
  const float* bfc = (const float*)d_in[6];
  char* ws = (char*)d_ws;

  hipMemsetAsync(ws + OFF_H0, 0, ((size_t)1 << 20) + 4096, stream);
  prep_wcat<<<2320, 256, 0, stream>>>(Wih, Whh, bih, bhh, ws);
  prep_xt<<<2048, 256, 0, stream>>>(x, ws);
  lstm_persist<<<256, 512, 0, stream>>>(ws);
  fc_kernel<<<256, 256, 0, stream>>>(ws, Wfc, bfc, (float*)d_out);
}

// Round 16
// 1823.999 us; speedup vs baseline: 1.4697x; 1.0487x over previous
//
#include <hip/hip_runtime.h>
#include <stdint.h>
#include <stddef.h>

typedef __attribute__((ext_vector_type(8))) _Float16 half8;
typedef __attribute__((ext_vector_type(8))) unsigned short ushort8;
typedef __attribute__((ext_vector_type(4))) float f4;
typedef __attribute__((ext_vector_type(2))) float f2;

#define AS1 __attribute__((address_space(1)))
#define AS3 __attribute__((address_space(3)))

namespace {
constexpr int kSteps = 255;   // reference iterates t = 0 .. T-2
constexpr int KTOT = 1152;    // 1024 (h) + 128 (x)

// workspace layout (bytes); total ~45 MB
// h layout: [group(16)][ub(32)][row(32)][u(32)] fp16 -> 2KB block slices
constexpr size_t OFF_H0   = 0;                                   // 1 MB  h ping
constexpr size_t OFF_CNT  = (size_t)1 << 20;                     // 4 KB  counters (16 x 64B)
constexpr size_t OFF_H1   = ((size_t)1 << 20) + 4096;            // 1 MB  h pong
constexpr size_t OFF_BSUM = OFF_H1 + ((size_t)1 << 20);          // 16 KB b_ih+b_hh (fp32)
constexpr size_t OFF_WCAT = OFF_BSUM + 16384;                    // 9.4 MB fp16 [4096][1152]
constexpr size_t OFF_XT   = OFF_WCAT + (size_t)4096 * KTOT * 2;  // 33.4 MB fp16 [255][512][128]
}

__device__ __forceinline__ unsigned short f2h(float f) {
  _Float16 h = (_Float16)f;
  return __builtin_bit_cast(unsigned short, h);
}
__device__ __forceinline__ float h2f(unsigned short s) {
  return (float)__builtin_bit_cast(_Float16, s);
}

// ---------- prep 1: Wcat fp16 + bsum ----------
__global__ void prep_wcat(const float* __restrict__ Wih, const float* __restrict__ Whh,
                          const float* __restrict__ bih, const float* __restrict__ bhh,
                          char* __restrict__ ws) {
  if (blockIdx.x < 2304) {
    unsigned gid = blockIdx.x * 256 + threadIdx.x;
    unsigned row = gid / 144, cc = gid % 144;
    const float* src = (cc < 128) ? (Whh + (size_t)row * 1024 + (size_t)cc * 8)
                                  : (Wih + (size_t)row * 128 + (size_t)(cc - 128) * 8);
    ushort8 o;
#pragma unroll
    for (int j = 0; j < 8; j++) o[j] = f2h(src[j]);
    *(ushort8*)((unsigned short*)(ws + OFF_WCAT) + (size_t)row * KTOT + cc * 8) = o;
  } else {
    int i = (blockIdx.x - 2304) * 256 + threadIdx.x;
    ((float*)(ws + OFF_BSUM))[i] = bih[i] + bhh[i];
  }
}

// ---------- prep 2: xT[t][b][i] = fp16(x[b][i][t]) ----------
__global__ void prep_xt(const float* __restrict__ x, char* __restrict__ ws) {
  unsigned short* xT = (unsigned short*)(ws + OFF_XT);
  __shared__ unsigned short tile[128][72];
  const int b = blockIdx.x >> 2;
  const int t0 = (blockIdx.x & 3) * 64;
  const int wv = threadIdx.x >> 6, tl = threadIdx.x & 63;
  if (t0 + tl < 255) {
#pragma unroll
    for (int ii = 0; ii < 32; ii++) {
      int i = wv + ii * 4;
      tile[i][tl] = f2h(x[((size_t)b * 128 + i) * 256 + t0 + tl]);
    }
  }
  __syncthreads();
  const int tl2 = threadIdx.x >> 4, ic = threadIdx.x & 15;
#pragma unroll
  for (int pp = 0; pp < 4; pp++) {
    int tloc = pp * 16 + tl2;
    int t = t0 + tloc;
    if (t < 255) {
      ushort8 v;
#pragma unroll
      for (int j = 0; j < 8; j++) v[j] = tile[ic * 8 + j][tloc];
      *(ushort8*)&xT[((size_t)t * 512 + b) * 128 + ic * 8] = v;
    }
  }
}

// ---------- persistent LSTM kernel: DUAL-CHAIN, cross-pipelined ----------
// grid 256 = (bid&7) -> groups {g, g+8} (both on XCD g), bid>>3 -> 32-unit tile.
// Per iteration: COMPUTE A (0 barriers, ring A resident) -> spinB+sync (doubles as
// pre-exchange barrier) -> STAGE ring B (flies under A's exchange) -> EXCH A ->
// same for B (staging ring A for t+1). 6 barriers/iter (was 16), no WAITBARs.
// x feeds MFMA straight from global->regs (frees buf7; ring holds all 8 h-chunks).
// Coherence (r8/r15-proven, no inv): h stores write-through sc0 sc1; h loads SC0;
// relaxed release after vmcnt(0) drain.
__global__ __launch_bounds__(512) __attribute__((amdgpu_waves_per_eu(2, 2)))
void lstm_persist(char* __restrict__ ws) {
  const unsigned short* __restrict__ wcat = (const unsigned short*)(ws + OFF_WCAT);
  const float* __restrict__ bsum = (const float*)(ws + OFF_BSUM);
  const unsigned short* __restrict__ xT = (const unsigned short*)(ws + OFF_XT);
  unsigned short* h0 = (unsigned short*)(ws + OFF_H0);
  unsigned short* h1 = (unsigned short*)(ws + OFF_H1);

  __shared__ __align__(16) char lds[131072];   // 2 rings x (8 bufs x 8KB); exchange reuses ring

  const int tid = threadIdx.x;
  const int lane = tid & 63;
  const int w = tid >> 6;
  const int wk = w & 3;           // K slice (32 cols of each 128-col chunk)
  const int wn = w >> 2;          // N half (64 of 128 gate cols)
  const int l15 = lane & 15, l4 = lane >> 4;
  const int gA = blockIdx.x & 7;       // chain A group (XCD-aligned)
  const int gB = gA + 8;               // chain B group (same XCD)
  const int cblk = blockIdx.x >> 3;    // unit tile 0..31
  const int U0 = cblk * 32;
  int* cntA = (int*)(ws + OFF_CNT) + gA * 16;
  int* cntB = (int*)(ws + OFF_CNT) + gB * 16;

  // ---- weight fragments -> registers. col n = wn*64+nf*16+l15 = unit*4+gate ----
  half8 bf[9][4];   // 144 regs, shared by both chains
  float bseed[4];
#pragma unroll
  for (int nf = 0; nf < 4; nf++) {
    int u = wn * 16 + nf * 4 + (l15 >> 2);
    int R = (l15 & 3) * 1024 + U0 + u;          // PyTorch gate order i,f,g,o
    float b = bsum[R];
    bseed[nf] = (wk == 0) ? b : 0.f;            // 4-way K reduce: one slice seeds bias
#pragma unroll
    for (int c = 0; c < 9; c++)
      bf[c][nf] = *(const half8*)&wcat[(size_t)R * KTOT + c * 128 + wk * 32 + l4 * 8];
  }

  // ---- staging: chunk 8KB = 8 slots of 1KB; slot = w (1 load/wave/chunk) ----
  // LDS (row, c16) holds G(row, c16 ^ (row&7)); source pre-inverse-swizzled (rule #21).
  const int srow = w * 4 + (lane >> 4);          // 0..31
  const int scg = (lane & 15) ^ (srow & 7);
  const int hoff1 = (scg >> 2) * 1024 + srow * 32 + (scg & 3) * 8;   // + c*4096 per chunk
  // A ds_read: row = m*16+l15, c16 = (wk*4+l4) ^ (l15&7); a1 at +4096 (m=1)
  const int aBase = l15 * 256 + (((wk * 4 + l4) ^ (l15 & 7)) * 16);
  const int xco = (wk * 4 + l4) * 8;             // x direct-to-reg column (halves)

  // exchange constants. writer: n = wn*64+nf*16+l15 (0..127), rf = m*4+l4 (0..7)
  int nb8[4], hnw[4];
#pragma unroll
  for (int nf = 0; nf < 4; nf++) {
    int n = wn * 64 + nf * 16 + l15;
    nb8[nf] = n * 8;
    hnw[nf] = (n ^ (n >> 3)) & 7;
  }
  // reader: thread owns (unit uu, rows qr*4+hi*2 .. +1); float2 reads per slice
  const int uu = tid & 31;
  const int qr = (tid >> 5) & 7;
  const int hi = (tid >> 8) & 1;
  int ro2[4];
#pragma unroll
  for (int g2 = 0; g2 < 4; g2++) {
    int n = 4 * uu + g2;
    ro2[g2] = (n * 8 + (qr ^ ((n ^ (n >> 3)) & 7))) * 16 + hi * 8;
  }
  const size_t hbA = ((size_t)(gA * 32 + cblk) * 32 + (qr * 4 + hi * 2)) * 32 + uu;
  const size_t hbB = ((size_t)(gB * 32 + cblk) * 32 + (qr * 4 + hi * 2)) * 32 + uu;

  f4 acc[2][4];
  half8 xa0, xa1, xb0, xb1;                     // x fragments (global->reg, no LDS)
  float cA0 = 0.f, cA1 = 0.f, cB0 = 0.f, cB1 = 0.f;

#define STG(HS, C, RB, BUF) \
  __builtin_amdgcn_global_load_lds( \
      (const AS1 void*)((HS) + hoff1 + (C) * 4096), \
      (AS3 void*)(lds + (RB) + (BUF) * 8192 + w * 1024), 16, 0, 1)

#define STG_RING(HS, RB) do { \
    STG(HS, 0, RB, 0); STG(HS, 1, RB, 1); STG(HS, 2, RB, 2); STG(HS, 3, RB, 3); \
    STG(HS, 4, RB, 4); STG(HS, 5, RB, 5); STG(HS, 6, RB, 6); STG(HS, 7, RB, 7); \
  } while (0)

#define MFMA8(A0, A1, C) do { \
    acc[0][0] = __builtin_amdgcn_mfma_f32_16x16x32_f16(A0, bf[C][0], acc[0][0], 0, 0, 0); \
    acc[0][1] = __builtin_amdgcn_mfma_f32_16x16x32_f16(A0, bf[C][1], acc[0][1], 0, 0, 0); \
    acc[0][2] = __builtin_amdgcn_mfma_f32_16x16x32_f16(A0, bf[C][2], acc[0][2], 0, 0, 0); \
    acc[0][3] = __builtin_amdgcn_mfma_f32_16x16x32_f16(A0, bf[C][3], acc[0][3], 0, 0, 0); \
    acc[1][0] = __builtin_amdgcn_mfma_f32_16x16x32_f16(A1, bf[C][0], acc[1][0], 0, 0, 0); \
    acc[1][1] = __builtin_amdgcn_mfma_f32_16x16x32_f16(A1, bf[C][1], acc[1][1], 0, 0, 0); \
    acc[1][2] = __builtin_amdgcn_mfma_f32_16x16x32_f16(A1, bf[C][2], acc[1][2], 0, 0, 0); \
    acc[1][3] = __builtin_amdgcn_mfma_f32_16x16x32_f16(A1, bf[C][3], acc[1][3], 0, 0, 0); \
  } while (0)

#define CMP(C, RB) do { \
    const char* _b = lds + (RB) + (C) * 8192 + aBase; \
    half8 a0 = *(const half8*)(_b); \
    half8 a1 = *(const half8*)(_b + 4096); \
    MFMA8(a0, a1, C); \
  } while (0)

#define COMPUTE_ALL(RB, XA0, XA1) do { \
    MFMA8(XA0, XA1, 8); \
    CMP(0, RB); CMP(1, RB); CMP(2, RB); CMP(3, RB); \
    CMP(4, RB); CMP(5, RB); CMP(6, RB); CMP(7, RB); \
  } while (0)

#define INIT_ACC do { \
    _Pragma("unroll") \
    for (int m = 0; m < 2; m++) \
      _Pragma("unroll") \
      for (int nf = 0; nf < 4; nf++) \
        acc[m][nf] = (f4){bseed[nf], bseed[nf], bseed[nf], bseed[nf]}; \
  } while (0)

#define SPIN(CNTP, TGT) do { \
    if (tid == 0) { \
      int guard = 1 << 18; \
      while (guard--) { \
        int c; \
        asm volatile("global_load_dword %0, %1, off sc0 sc1\n\ts_waitcnt vmcnt(0)" \
                     : "=v"(c) : "v"(CNTP) : "memory"); \
        if (c >= (TGT)) break; \
        __builtin_amdgcn_s_sleep(1); \
      } \
    } \
    __syncthreads(); /* joins; also = pre-exchange barrier (compute reads drained) */ \
  } while (0)

// exchange (in own ring) + activation + h store + release; 2 barriers
#define EXCHFIN(RB, HDST, HB, C0, C1, CNTP) do { \
    _Pragma("unroll") \
    for (int m = 0; m < 2; m++) \
      _Pragma("unroll") \
      for (int nf = 0; nf < 4; nf++) { \
        int rf = m * 4 + l4; \
        *(f4*)(lds + (RB) + wk * 16384 + (size_t)(nb8[nf] + (rf ^ hnw[nf])) * 16) = acc[m][nf]; \
      } \
    __syncthreads(); \
    { \
      f2 gsv[4]; \
      _Pragma("unroll") \
      for (int g2 = 0; g2 < 4; g2++) { \
        f2 s0 = *(const f2*)(lds + (RB) + ro2[g2]); \
        f2 s1 = *(const f2*)(lds + (RB) + 16384 + ro2[g2]); \
        f2 s2 = *(const f2*)(lds + (RB) + 32768 + ro2[g2]); \
        f2 s3 = *(const f2*)(lds + (RB) + 49152 + ro2[g2]); \
        gsv[g2] = (s0 + s1) + (s2 + s3); \
      } \
      float ig0 = 1.f / (1.f + __expf(-gsv[0][0])); \
      float fg0 = 1.f / (1.f + __expf(-gsv[1][0])); \
      float gg0 = 2.f / (1.f + __expf(-2.f * gsv[2][0])) - 1.f; \
      float og0 = 1.f / (1.f + __expf(-gsv[3][0])); \
      float cn0 = fg0 * (C0) + ig0 * gg0; \
      (C0) = cn0; \
      float th0 = 2.f / (1.f + __expf(-2.f * cn0)) - 1.f; \
      unsigned short* hp0 = (HDST) + (HB); \
      unsigned hv0 = f2h(og0 * th0); \
      asm volatile("global_store_short %0, %1, off sc0 sc1" :: "v"(hp0), "v"(hv0) : "memory"); \
      float ig1 = 1.f / (1.f + __expf(-gsv[0][1])); \
      float fg1 = 1.f / (1.f + __expf(-gsv[1][1])); \
      float gg1 = 2.f / (1.f + __expf(-2.f * gsv[2][1])) - 1.f; \
      float og1 = 1.f / (1.f + __expf(-gsv[3][1])); \
      float cn1 = fg1 * (C1) + ig1 * gg1; \
      (C1) = cn1; \
      float th1 = 2.f / (1.f + __expf(-2.f * cn1)) - 1.f; \
      unsigned short* hp1 = (HDST) + (HB) + 32; \
      unsigned hv1 = f2h(og1 * th1); \
      asm volatile("global_store_short %0, %1, off sc0 sc1" :: "v"(hp1), "v"(hv1) : "memory"); \
    } \
    __syncthreads(); /* drains h stores (vmcnt0, write-through ack) + exch reads + staging */ \
    if (tid == 0) \
      __hip_atomic_fetch_add(CNTP, 1, __ATOMIC_RELAXED, __HIP_MEMORY_SCOPE_AGENT); \
  } while (0)

  // ---- prologue: stage A(0) (h0 is zeroed; gate trivial) + x fragment ----
  STG_RING(h0 + gA * 32768, 0);
  {
    const unsigned short* xp = xT + (gA * 32 + l15) * 128 + xco;
    xa0 = *(const half8*)xp; xa1 = *(const half8*)(xp + 2048);
  }
  __syncthreads();   // drain prologue staging

#pragma unroll 1
  for (int t = 0; t < kSteps; t++) {
    const unsigned short* hsrc = (t & 1) ? h1 : h0;
    unsigned short* hdst = (t & 1) ? h0 : h1;

    // ---- A phase: compute A(t); stage B(t) under A's exchange ----
    INIT_ACC;
    COMPUTE_ALL(0, xa0, xa1);
    SPIN(cntB, 32 * t);                       // gate B(t) staging; pre-exchange barrier
    STG_RING(hsrc + gB * 32768, 65536);
    {
      const unsigned short* xp = xT + (size_t)t * 65536 + (gB * 32 + l15) * 128 + xco;
      xb0 = *(const half8*)xp; xb1 = *(const half8*)(xp + 2048);
    }
    EXCHFIN(0, hdst, hbA, cA0, cA1, cntA);    // release A(t)

    // ---- B phase: compute B(t); stage A(t+1) under B's exchange ----
    INIT_ACC;
    COMPUTE_ALL(65536, xb0, xb1);
    if (t + 1 < kSteps) {
      SPIN(cntA, 32 * (t + 1));               // gate A(t+1) staging; pre-exchange barrier
      STG_RING(hdst + gA * 32768, 0);         // hsrc(t+1) = hdst(t)
      const unsigned short* xp = xT + (size_t)(t + 1) * 65536 + (gA * 32 + l15) * 128 + xco;
      xa0 = *(const half8*)xp; xa1 = *(const half8*)(xp + 2048);
    } else {
      __syncthreads();                        // pre-exchange barrier only
    }
    EXCHFIN(65536, hdst, hbB, cB0, cB1, cntB);
  }
#undef EXCHFIN
#undef SPIN
#undef INIT_ACC
#undef COMPUTE_ALL
#undef CMP
#undef MFMA8
#undef STG_RING
#undef STG
}

// ---------- FC: out = h_last @ W_fc^T + b_fc ----------
__global__ void fc_kernel(const char* __restrict__ ws, const float* __restrict__ Wfc,
                          const float* __restrict__ bfc, float* __restrict__ out) {
  const unsigned short* h = (const unsigned short*)(ws + OFF_H1);  // t=254 writes h1
  int o = threadIdx.x & 127;
  int b = blockIdx.x * 2 + (threadIdx.x >> 7);
  const float* wrow = Wfc + (size_t)o * 1024;
  float acc = bfc[o];
  int gb = b >> 5, rb = b & 31;
#pragma unroll 4
  for (int k = 0; k < 1024; k += 8) {
    ushort8 hv = *(const ushort8*)&h[(((size_t)(gb * 32 + (k >> 5)) * 32 + rb) * 32) + (k & 31)];
    f4 w0 = *(const f4*)&wrow[k];
    f4 w1 = *(const f4*)&wrow[k + 4];
#pragma unroll
    for (int j = 0; j < 4; j++) acc += h2f(hv[j]) * w0[j];
#pragma unroll
    for (int j = 0; j < 4; j++) acc += h2f(hv[4 + j]) * w1[j];
  }
  out[(size_t)b * 128 + o] = acc;
}

extern "C" void kernel_launch(void* const* d_in, const int* in_sizes, int n_in,
                              void* d_out, int out_size, void* d_ws, size_t ws_size,
                              hipStream_t stream) {
  const float* x   = (const float*)d_in[0];
  const float* Wih = (const float*)d_in[1];
  const float* Whh = (const float*)d_in[2];
  const float* bih = (const float*)d_in[3];
  const float* bhh = (const float*)d_in[4];
  const float* Wfc = (const float*)d_in[5];
  const float* bfc = (const float*)d_in[6];
  char* ws = (char*)d_ws;

  hipMemsetAsync(ws + OFF_H0, 0, ((size_t)1 << 20) + 4096, stream);
  prep_wcat<<<2320, 256, 0, stream>>>(Wih, Whh, bih, bhh, ws);
  prep_xt<<<2048, 256, 0, stream>>>(x, ws);
  lstm_persist<<<256, 512, 0, stream>>>(ws);
  fc_kernel<<<256, 256, 0, stream>>>(ws, Wfc, bfc, (float*)d_out);
}